// Round 1
// baseline (2297.756 us; speedup 1.0000x reference)
//
#include <hip/hip_runtime.h>
#include <hip/hip_bf16.h>

typedef __hip_bfloat16 bf16;

static constexpr int B_   = 8;
static constexpr int Lq_  = 10000;
static constexpr int C_   = 256;
static constexpr int NH_  = 8;
static constexpr int NP_  = 4;
static constexpr int DFF_ = 1024;
static constexpr int HIMG = 100;
static constexpr int WIMG = 100;
static constexpr int LIN  = 10000;   // H*W

__device__ __forceinline__ float ldf(const float* p) { return *p; }
__device__ __forceinline__ float ldf(const bf16* p)  { return __bfloat162float(*p); }
__device__ __forceinline__ void  stf(float* p, float v) { *p = v; }
__device__ __forceinline__ void  stf(bf16* p, float v)  { *p = __float2bfloat16(v); }

// ---------------------------------------------------------------------------
// Generic tiled GEMM:  C[M][N] = A[M][K] @ B[K][N] + bias[N]  (optional ReLU)
// A row-major with lda == K (all our A's are contiguous). B row-major ldb.
// 64x64 tile, 256 threads, 4x4 micro-tile, BK=16, f32 accumulation.
// ---------------------------------------------------------------------------
template <typename TA, typename TB, typename TC, bool RELU>
__global__ __launch_bounds__(256) void gemm_bias(
    const TA* __restrict__ A, const TB* __restrict__ Bm,
    const float* __restrict__ bias, TC* __restrict__ C,
    int M, int N, int K, int ldb, int ldc)
{
    __shared__ float As[16][64];   // [k][m]
    __shared__ float Bs[16][64];   // [k][n]

    const int tid = threadIdx.x;
    const int tx  = tid & 15;      // 0..15 -> 4 cols each
    const int ty  = tid >> 4;      // 0..15 -> 4 rows each
    const int m0  = blockIdx.y * 64;
    const int n0  = blockIdx.x * 64;

    const int arow = tid >> 2;          // 0..63
    const int ak   = (tid & 3) << 2;    // 0,4,8,12
    const int bk   = tid >> 4;          // 0..15
    const int bn   = (tid & 15) << 2;   // 0..60

    float acc[4][4] = {};

    for (int k0 = 0; k0 < K; k0 += 16) {
        // stage A tile (transposed into LDS)
        {
            const int gm = m0 + arow;
            float a0 = 0.f, a1 = 0.f, a2 = 0.f, a3 = 0.f;
            if (gm < M) {
                const TA* ap = A + (size_t)gm * K + k0 + ak;
                a0 = ldf(ap + 0); a1 = ldf(ap + 1); a2 = ldf(ap + 2); a3 = ldf(ap + 3);
            }
            As[ak + 0][arow] = a0;
            As[ak + 1][arow] = a1;
            As[ak + 2][arow] = a2;
            As[ak + 3][arow] = a3;
        }
        // stage B tile
        {
            const int gn = n0 + bn;
            const TB* bp = Bm + (size_t)(k0 + bk) * ldb + gn;
            Bs[bk][bn + 0] = (gn + 0 < N) ? ldf(bp + 0) : 0.f;
            Bs[bk][bn + 1] = (gn + 1 < N) ? ldf(bp + 1) : 0.f;
            Bs[bk][bn + 2] = (gn + 2 < N) ? ldf(bp + 2) : 0.f;
            Bs[bk][bn + 3] = (gn + 3 < N) ? ldf(bp + 3) : 0.f;
        }
        __syncthreads();

#pragma unroll
        for (int k = 0; k < 16; ++k) {
            const float4 av = *reinterpret_cast<const float4*>(&As[k][ty << 2]);
            const float4 bv = *reinterpret_cast<const float4*>(&Bs[k][tx << 2]);
            const float a[4] = {av.x, av.y, av.z, av.w};
            const float b[4] = {bv.x, bv.y, bv.z, bv.w};
#pragma unroll
            for (int i = 0; i < 4; ++i)
#pragma unroll
                for (int j = 0; j < 4; ++j) acc[i][j] += a[i] * b[j];
        }
        __syncthreads();
    }

#pragma unroll
    for (int i = 0; i < 4; ++i) {
        const int gm = m0 + (ty << 2) + i;
        if (gm >= M) continue;
#pragma unroll
        for (int j = 0; j < 4; ++j) {
            const int gn = n0 + (tx << 2) + j;
            if (gn >= N) continue;
            float v = acc[i][j] + bias[gn];
            if (RELU) v = fmaxf(v, 0.f);
            stf(&C[(size_t)gm * ldc + gn], v);
        }
    }
}

// ---------------------------------------------------------------------------
// Bilinear sampling + attention-weight combine.
// One 32-lane group per (b,q,h); lane = HD channel (32 consecutive bf16 =
// 64 B coalesced gather per corner). value layout [b][pix][h][d].
// oaw row layout per token: [0..63] = offsets (h,p,{x,y}), [64..95] = aw logits.
// ---------------------------------------------------------------------------
__device__ __forceinline__ float corner_fetch(const bf16* vb, int xi, int yi, float w)
{
    if (xi < 0 || xi >= WIMG || yi < 0 || yi >= HIMG) return 0.f;
    return w * __bfloat162float(vb[(size_t)(yi * WIMG + xi) * C_]);
}

__global__ __launch_bounds__(256) void sample_attn(
    const bf16* __restrict__ val, const float* __restrict__ oaw,
    const float* __restrict__ refp, bf16* __restrict__ attn)
{
    const int lane = threadIdx.x & 31;
    const int gid  = blockIdx.x * 8 + (threadIdx.x >> 5);  // (b*Lq+q)*NH + h
    const int h    = gid & (NH_ - 1);
    const int bq   = gid >> 3;
    if (bq >= B_ * Lq_) return;

    const float* row = oaw + (size_t)bq * 96;
    const float rx = refp[(size_t)bq * 2 + 0] * (float)WIMG;
    const float ry = refp[(size_t)bq * 2 + 1] * (float)HIMG;

    // softmax over NP=4 attention logits
    const float a0 = row[64 + h * 4 + 0];
    const float a1 = row[64 + h * 4 + 1];
    const float a2 = row[64 + h * 4 + 2];
    const float a3 = row[64 + h * 4 + 3];
    const float mx = fmaxf(fmaxf(a0, a1), fmaxf(a2, a3));
    const float e0 = expf(a0 - mx), e1 = expf(a1 - mx), e2 = expf(a2 - mx), e3 = expf(a3 - mx);
    const float inv = 1.f / (e0 + e1 + e2 + e3);
    const float w4[4] = {e0 * inv, e1 * inv, e2 * inv, e3 * inv};

    const int b = bq / Lq_;
    const bf16* vb = val + (size_t)b * LIN * C_ + h * 32 + lane;

    float acc = 0.f;
#pragma unroll
    for (int p = 0; p < NP_; ++p) {
        const float ox = row[(h * 4 + p) * 2 + 0];
        const float oy = row[(h * 4 + p) * 2 + 1];
        const float x = rx + ox - 0.5f;
        const float y = ry + oy - 0.5f;
        const float x0f = floorf(x), y0f = floorf(y);
        const float lx = x - x0f, ly = y - y0f;
        const int x0 = (int)x0f, y0 = (int)y0f;
        const float wp = w4[p];
        acc += corner_fetch(vb, x0,     y0,     wp * (1.f - lx) * (1.f - ly));
        acc += corner_fetch(vb, x0 + 1, y0,     wp * lx         * (1.f - ly));
        acc += corner_fetch(vb, x0,     y0 + 1, wp * (1.f - lx) * ly);
        acc += corner_fetch(vb, x0 + 1, y0 + 1, wp * lx         * ly);
    }
    attn[(size_t)bq * C_ + h * 32 + lane] = __float2bfloat16(acc);
}

// ---------------------------------------------------------------------------
// Fused residual + LayerNorm:  out = LN(x + y) * g + be.  One wave per row
// (C=256 -> 4 f32 per lane). x is f32, y is bf16.
// ---------------------------------------------------------------------------
__global__ __launch_bounds__(256) void ln_add(
    const float* __restrict__ x, const bf16* __restrict__ y,
    const float* __restrict__ g, const float* __restrict__ be,
    float* __restrict__ out, int rows)
{
    const int row  = blockIdx.x * 4 + (threadIdx.x >> 6);
    const int lane = threadIdx.x & 63;
    if (row >= rows) return;

    const float4 xv = *reinterpret_cast<const float4*>(x + (size_t)row * C_ + (lane << 2));
    const ushort4 yv = *reinterpret_cast<const ushort4*>(
        reinterpret_cast<const unsigned short*>(y) + (size_t)row * C_ + (lane << 2));

    float v[4];
    v[0] = xv.x + __uint_as_float((unsigned)yv.x << 16);
    v[1] = xv.y + __uint_as_float((unsigned)yv.y << 16);
    v[2] = xv.z + __uint_as_float((unsigned)yv.z << 16);
    v[3] = xv.w + __uint_as_float((unsigned)yv.w << 16);

    float s  = v[0] + v[1] + v[2] + v[3];
    float s2 = v[0] * v[0] + v[1] * v[1] + v[2] * v[2] + v[3] * v[3];
#pragma unroll
    for (int o = 32; o >= 1; o >>= 1) {
        s  += __shfl_xor(s, o);
        s2 += __shfl_xor(s2, o);
    }
    const float mean = s * (1.f / 256.f);
    const float var  = fmaxf(s2 * (1.f / 256.f) - mean * mean, 0.f);
    const float rstd = rsqrtf(var + 1e-5f);

    const float4 gv = *reinterpret_cast<const float4*>(g  + (lane << 2));
    const float4 bv = *reinterpret_cast<const float4*>(be + (lane << 2));
    float4 o4;
    o4.x = (v[0] - mean) * rstd * gv.x + bv.x;
    o4.y = (v[1] - mean) * rstd * gv.y + bv.y;
    o4.z = (v[2] - mean) * rstd * gv.z + bv.z;
    o4.w = (v[3] - mean) * rstd * gv.w + bv.w;
    *reinterpret_cast<float4*>(out + (size_t)row * C_ + (lane << 2)) = o4;
}

// ---------------------------------------------------------------------------
extern "C" void kernel_launch(void* const* d_in, const int* in_sizes, int n_in,
                              void* d_out, int out_size, void* d_ws, size_t ws_size,
                              hipStream_t stream)
{
    const float* query = (const float*)d_in[0];
    const float* src   = (const float*)d_in[1];
    const float* refp  = (const float*)d_in[2];
    // d_in[3] spatial_shapes, d_in[4] level_start_index: constants, hardcoded.
    const float* W_off = (const float*)d_in[5];
    const float* b_off = (const float*)d_in[6];
    const float* W_aw  = (const float*)d_in[7];
    const float* b_aw  = (const float*)d_in[8];
    const float* W_val = (const float*)d_in[9];
    const float* b_val = (const float*)d_in[10];
    const float* W_out = (const float*)d_in[11];
    const float* b_out = (const float*)d_in[12];
    const float* g1    = (const float*)d_in[13];
    const float* be1   = (const float*)d_in[14];
    const float* W1    = (const float*)d_in[15];
    const float* b1    = (const float*)d_in[16];
    const float* W2    = (const float*)d_in[17];
    const float* b2    = (const float*)d_in[18];
    const float* g2    = (const float*)d_in[19];
    const float* be2   = (const float*)d_in[20];
    float* out = (float*)d_out;

    char* ws = (char*)d_ws;
    const int R = B_ * Lq_;  // 80000

    // Workspace layout (bytes), with lifetime-based reuse:
    //   [0, 40.96M)      val bf16 (80000*256)        -> later: ffnout bf16
    //   [40.96M, 71.68M) oaw f32  (80000*96)         -> later: h bf16 (10000*1024)
    //   [71.68M, 112.64M)  attn bf16
    //   [112.64M, 153.6M)  attnout bf16
    //   [153.6M, 235.52M)  q1 f32
    bf16*  val   = (bf16*)(ws + 0);
    bf16*  ffno  = (bf16*)(ws + 0);
    float* oaw   = (float*)(ws + 40960000);
    bf16*  h     = (bf16*)(ws + 40960000);
    bf16*  attn  = (bf16*)(ws + 71680000);
    bf16*  attno = (bf16*)(ws + 112640000);
    float* q1    = (float*)(ws + 153600000);

    const dim3 blk(256);

    // 1. value = src @ W_val + b_val   [80000,256]x[256,256] -> bf16
    gemm_bias<float, float, bf16, false><<<dim3(4, 1250), blk, 0, stream>>>(
        src, W_val, b_val, val, R, 256, 256, 256, 256);

    // 2. offsets and attention logits: query @ [W_off | W_aw] -> oaw [80000,96]
    gemm_bias<float, float, float, false><<<dim3(1, 1250), blk, 0, stream>>>(
        query, W_off, b_off, oaw, R, 64, 256, 64, 96);
    gemm_bias<float, float, float, false><<<dim3(1, 1250), blk, 0, stream>>>(
        query, W_aw, b_aw, oaw + 64, R, 32, 256, 32, 96);

    // 3. bilinear sampling + combine -> attn [80000,256] bf16
    sample_attn<<<dim3(R * NH_ / 8), blk, 0, stream>>>(val, oaw, refp, attn);

    // 4. output projection: attn @ W_out + b_out -> attnout bf16
    gemm_bias<bf16, float, bf16, false><<<dim3(4, 1250), blk, 0, stream>>>(
        attn, W_out, b_out, attno, R, 256, 256, 256, 256);

    // 5. q1 = LN(query + attnout)
    ln_add<<<dim3(R / 4), blk, 0, stream>>>(query, attno, g1, be1, q1, R);

    // 6. FFN, chunked per batch to bound workspace: h = relu(q1@W1+b1); ffn = h@W2+b2
    for (int b = 0; b < B_; ++b) {
        const float* q1b = q1 + (size_t)b * Lq_ * C_;
        bf16* ffb = ffno + (size_t)b * Lq_ * C_;
        gemm_bias<float, float, bf16, true><<<dim3(16, 157), blk, 0, stream>>>(
            q1b, W1, b1, h, Lq_, DFF_, 256, DFF_, DFF_);
        gemm_bias<bf16, float, bf16, false><<<dim3(4, 157), blk, 0, stream>>>(
            h, W2, b2, ffb, Lq_, 256, DFF_, 256, 256);
    }

    // 7. out = LN(q1 + ffn)
    ln_add<<<dim3(R / 4), blk, 0, stream>>>(q1, ffno, g2, be2, out, R);
}

// Round 2
// 726.310 us; speedup vs baseline: 3.1636x; 3.1636x over previous
//
#include <hip/hip_runtime.h>
#include <hip/hip_bf16.h>

typedef __hip_bfloat16 bf16;
typedef unsigned short u16;
typedef short short8 __attribute__((ext_vector_type(8)));
typedef float f32x4 __attribute__((ext_vector_type(4)));

static constexpr int B_   = 8;
static constexpr int Lq_  = 10000;
static constexpr int C_   = 256;
static constexpr int NH_  = 8;
static constexpr int NP_  = 4;
static constexpr int DFF_ = 1024;
static constexpr int HIMG = 100;
static constexpr int WIMG = 100;
static constexpr int LIN  = 10000;   // H*W

__device__ __forceinline__ u16 f2bf(float x) {
    union { bf16 b; u16 u; } cv; cv.b = __float2bfloat16(x); return cv.u;
}
__device__ __forceinline__ float bf2f(u16 u) {
    return __uint_as_float((unsigned)u << 16);
}
__device__ __forceinline__ void stf(float* p, float v) { *p = v; }
__device__ __forceinline__ void stf(bf16* p, float v)  { *p = __float2bfloat16(v); }

// Async global -> LDS, 16 B per lane. LDS dest must be wave-uniform base;
// HW writes base + lane*16 (guide §5 caveat m104).
__device__ __forceinline__ void gl_lds16(const void* g, void* l) {
    __builtin_amdgcn_global_load_lds(
        (const __attribute__((address_space(1))) void*)g,
        (__attribute__((address_space(3))) void*)l, 16, 0, 0);
}

// ---------------------------------------------------------------------------
// m97-structure bf16 MFMA GEMM. C[M][ldc] = A[M][K] @ B + bias (opt. ReLU).
// A: [M][K] bf16 row-major. Bt: [Npad][K] bf16 (B transposed), Npad = 128*gridDim.x.
// 256 threads = 4 waves (2x2), 128x128 tile, BK=32, 4x4 16x16x32 frags/wave.
// M must be a multiple of 128; K a multiple of 32. Store guarded by Nreal.
// ---------------------------------------------------------------------------
template <bool RELU, typename TC>
__global__ __launch_bounds__(256) void gemm_mfma(
    const u16* __restrict__ A, const u16* __restrict__ Bt,
    const float* __restrict__ bias, TC* __restrict__ C,
    int M, int K, int Nreal, int ldc)
{
    __shared__ __align__(16) u16 As[128 * 32];
    __shared__ __align__(16) u16 Bs[128 * 32];

    const int tid  = threadIdx.x;
    const int lane = tid & 63;
    const int w    = tid >> 6;
    const int wr   = (w >> 1) * 64;     // wave row offset in tile
    const int wc   = (w & 1) * 64;      // wave col offset in tile
    const int m0   = blockIdx.y * 128;
    const int n0   = blockIdx.x * 128;

    // staging: wave w owns rows [w*32, w*32+32); lane covers (lane>>2)-th row,
    // 16 B chunk (lane&3) of the 64 B row. Two loads per matrix per K-step.
    const int srow = lane >> 2;          // 0..15
    const int scol = (lane & 3) << 3;    // element offset 0,8,16,24

    const u16* aG = A  + (size_t)(m0 + w * 32 + srow) * K + scol;
    const u16* bG = Bt + (size_t)(n0 + w * 32 + srow) * K + scol;
    u16* aL0 = &As[(w * 32) * 32];
    u16* aL1 = &As[(w * 32 + 16) * 32];
    u16* bL0 = &Bs[(w * 32) * 32];
    u16* bL1 = &Bs[(w * 32 + 16) * 32];
    const size_t rstep = (size_t)16 * K;

    // fragment read addresses (fixed): row-major [128][32] bf16, 64 B rows
    const char* aR = (const char*)As + (wr + (lane & 15)) * 64 + (lane >> 4) * 16;
    const char* bR = (const char*)Bs + (wc + (lane & 15)) * 64 + (lane >> 4) * 16;

    f32x4 acc[4][4];
#pragma unroll
    for (int i = 0; i < 4; ++i)
#pragma unroll
        for (int j = 0; j < 4; ++j) acc[i][j] = f32x4{0.f, 0.f, 0.f, 0.f};

    for (int k0 = 0; k0 < K; k0 += 32) {
        gl_lds16(aG + k0,         aL0);
        gl_lds16(aG + k0 + rstep, aL1);
        gl_lds16(bG + k0,         bL0);
        gl_lds16(bG + k0 + rstep, bL1);
        __syncthreads();   // compiler drains vmcnt before s_barrier

        short8 af[4], bfr[4];
#pragma unroll
        for (int m = 0; m < 4; ++m) af[m]  = *(const short8*)(aR + m * 16 * 64);
#pragma unroll
        for (int n = 0; n < 4; ++n) bfr[n] = *(const short8*)(bR + n * 16 * 64);
#pragma unroll
        for (int m = 0; m < 4; ++m)
#pragma unroll
            for (int n = 0; n < 4; ++n)
                acc[m][n] = __builtin_amdgcn_mfma_f32_16x16x32_bf16(
                    af[m], bfr[n], acc[m][n], 0, 0, 0);
        __syncthreads();
    }

    // epilogue: C/D layout col = lane&15, row = (lane>>4)*4 + r  (m89/m91)
#pragma unroll
    for (int n = 0; n < 4; ++n) {
        const int gc = n0 + wc + n * 16 + (lane & 15);
        if (gc >= Nreal) continue;
        const float bv = bias[gc];
        const int gr0 = m0 + wr + (lane >> 4) * 4;
#pragma unroll
        for (int m = 0; m < 4; ++m) {
#pragma unroll
            for (int r = 0; r < 4; ++r) {
                float v = acc[m][n][r] + bv;
                if (RELU) v = fmaxf(v, 0.f);
                stf(&C[(size_t)(gr0 + m * 16 + r) * ldc + gc], v);
            }
        }
    }
}

// ---------------------------------------------------------------------------
// f32 -> bf16 bulk convert, 8 elems/thread
// ---------------------------------------------------------------------------
__global__ __launch_bounds__(256) void cvt_bf16(
    const float* __restrict__ in, u16* __restrict__ out, int n8)
{
    for (int i = blockIdx.x * 256 + threadIdx.x; i < n8; i += gridDim.x * 256) {
        const float4 v0 = *(const float4*)(in + (size_t)i * 8);
        const float4 v1 = *(const float4*)(in + (size_t)i * 8 + 4);
        union { short8 s; u16 u[8]; } o;
        o.u[0] = f2bf(v0.x); o.u[1] = f2bf(v0.y); o.u[2] = f2bf(v0.z); o.u[3] = f2bf(v0.w);
        o.u[4] = f2bf(v1.x); o.u[5] = f2bf(v1.y); o.u[6] = f2bf(v1.z); o.u[7] = f2bf(v1.w);
        *(short8*)(out + (size_t)i * 8) = o.s;
    }
}

// transpose+convert weight: Wt[n][k] = bf16(W[k][n]);  Wt is [N][K]
__global__ __launch_bounds__(256) void wprep(
    const float* __restrict__ W, u16* __restrict__ Wt, int K, int N)
{
    const int idx = blockIdx.x * 256 + threadIdx.x;
    if (idx >= N * K) return;
    const int n = idx / K;
    const int k = idx - n * K;
    Wt[idx] = f2bf(W[(size_t)k * N + n]);
}

// combined [W_off | W_aw] -> Wt [128][256] (rows 96..127 zero), bias [128]
__global__ __launch_bounds__(256) void prep_offaw(
    const float* __restrict__ Woff, const float* __restrict__ Waw,
    const float* __restrict__ boff, const float* __restrict__ baw,
    u16* __restrict__ Wt, float* __restrict__ bias)
{
    const int idx = blockIdx.x * 256 + threadIdx.x;   // 128*256 threads
    const int n = idx >> 8, k = idx & 255;
    float v = 0.f;
    if (n < 64)      v = Woff[k * 64 + n];
    else if (n < 96) v = Waw[k * 32 + (n - 64)];
    Wt[idx] = f2bf(v);
    if (idx < 128) bias[idx] = (idx < 64) ? boff[idx] : (idx < 96 ? baw[idx - 64] : 0.f);
}

// ---------------------------------------------------------------------------
// Bilinear sampling + attention-weight combine (unchanged from R1).
// ---------------------------------------------------------------------------
__device__ __forceinline__ float corner_fetch(const bf16* vb, int xi, int yi, float w)
{
    if (xi < 0 || xi >= WIMG || yi < 0 || yi >= HIMG) return 0.f;
    return w * __bfloat162float(vb[(size_t)(yi * WIMG + xi) * C_]);
}

__global__ __launch_bounds__(256) void sample_attn(
    const bf16* __restrict__ val, const float* __restrict__ oaw,
    const float* __restrict__ refp, bf16* __restrict__ attn)
{
    const int lane = threadIdx.x & 31;
    const int gid  = blockIdx.x * 8 + (threadIdx.x >> 5);  // (b*Lq+q)*NH + h
    const int h    = gid & (NH_ - 1);
    const int bq   = gid >> 3;
    if (bq >= B_ * Lq_) return;

    const float* row = oaw + (size_t)bq * 96;
    const float rx = refp[(size_t)bq * 2 + 0] * (float)WIMG;
    const float ry = refp[(size_t)bq * 2 + 1] * (float)HIMG;

    const float a0 = row[64 + h * 4 + 0];
    const float a1 = row[64 + h * 4 + 1];
    const float a2 = row[64 + h * 4 + 2];
    const float a3 = row[64 + h * 4 + 3];
    const float mx = fmaxf(fmaxf(a0, a1), fmaxf(a2, a3));
    const float e0 = expf(a0 - mx), e1 = expf(a1 - mx), e2 = expf(a2 - mx), e3 = expf(a3 - mx);
    const float inv = 1.f / (e0 + e1 + e2 + e3);
    const float w4[4] = {e0 * inv, e1 * inv, e2 * inv, e3 * inv};

    const int b = bq / Lq_;
    const bf16* vb = val + (size_t)b * LIN * C_ + h * 32 + lane;

    float acc = 0.f;
#pragma unroll
    for (int p = 0; p < NP_; ++p) {
        const float ox = row[(h * 4 + p) * 2 + 0];
        const float oy = row[(h * 4 + p) * 2 + 1];
        const float x = rx + ox - 0.5f;
        const float y = ry + oy - 0.5f;
        const float x0f = floorf(x), y0f = floorf(y);
        const float lx = x - x0f, ly = y - y0f;
        const int x0 = (int)x0f, y0 = (int)y0f;
        const float wp = w4[p];
        acc += corner_fetch(vb, x0,     y0,     wp * (1.f - lx) * (1.f - ly));
        acc += corner_fetch(vb, x0 + 1, y0,     wp * lx         * (1.f - ly));
        acc += corner_fetch(vb, x0,     y0 + 1, wp * (1.f - lx) * ly);
        acc += corner_fetch(vb, x0 + 1, y0 + 1, wp * lx         * ly);
    }
    attn[(size_t)bq * C_ + h * 32 + lane] = __float2bfloat16(acc);
}

// ---------------------------------------------------------------------------
// Fused residual + LayerNorm; optional secondary bf16 output (next GEMM's A).
// ---------------------------------------------------------------------------
__global__ __launch_bounds__(256) void ln_add(
    const float* __restrict__ x, const u16* __restrict__ y,
    const float* __restrict__ g, const float* __restrict__ be,
    float* __restrict__ out, u16* __restrict__ outb, int rows)
{
    const int row  = blockIdx.x * 4 + (threadIdx.x >> 6);
    const int lane = threadIdx.x & 63;
    if (row >= rows) return;

    const float4 xv = *(const float4*)(x + (size_t)row * C_ + (lane << 2));
    const ushort4 yv = *(const ushort4*)(y + (size_t)row * C_ + (lane << 2));

    float v[4];
    v[0] = xv.x + bf2f(yv.x);
    v[1] = xv.y + bf2f(yv.y);
    v[2] = xv.z + bf2f(yv.z);
    v[3] = xv.w + bf2f(yv.w);

    float s  = v[0] + v[1] + v[2] + v[3];
    float s2 = v[0] * v[0] + v[1] * v[1] + v[2] * v[2] + v[3] * v[3];
#pragma unroll
    for (int o = 32; o >= 1; o >>= 1) {
        s  += __shfl_xor(s, o);
        s2 += __shfl_xor(s2, o);
    }
    const float mean = s * (1.f / 256.f);
    const float var  = fmaxf(s2 * (1.f / 256.f) - mean * mean, 0.f);
    const float rstd = rsqrtf(var + 1e-5f);

    const float4 gv = *(const float4*)(g  + (lane << 2));
    const float4 bv = *(const float4*)(be + (lane << 2));
    float4 o4;
    o4.x = (v[0] - mean) * rstd * gv.x + bv.x;
    o4.y = (v[1] - mean) * rstd * gv.y + bv.y;
    o4.z = (v[2] - mean) * rstd * gv.z + bv.z;
    o4.w = (v[3] - mean) * rstd * gv.w + bv.w;
    *(float4*)(out + (size_t)row * C_ + (lane << 2)) = o4;

    if (outb) {
        ushort4 ob;
        ob.x = f2bf(o4.x); ob.y = f2bf(o4.y); ob.z = f2bf(o4.z); ob.w = f2bf(o4.w);
        *(ushort4*)(outb + (size_t)row * C_ + (lane << 2)) = ob;
    }
}

// ---------------------------------------------------------------------------
extern "C" void kernel_launch(void* const* d_in, const int* in_sizes, int n_in,
                              void* d_out, int out_size, void* d_ws, size_t ws_size,
                              hipStream_t stream)
{
    const float* query = (const float*)d_in[0];
    const float* src   = (const float*)d_in[1];
    const float* refp  = (const float*)d_in[2];
    const float* W_off = (const float*)d_in[5];
    const float* b_off = (const float*)d_in[6];
    const float* W_aw  = (const float*)d_in[7];
    const float* b_aw  = (const float*)d_in[8];
    const float* W_val = (const float*)d_in[9];
    const float* b_val = (const float*)d_in[10];
    const float* W_out = (const float*)d_in[11];
    const float* b_out = (const float*)d_in[12];
    const float* g1    = (const float*)d_in[13];
    const float* be1   = (const float*)d_in[14];
    const float* W1    = (const float*)d_in[15];
    const float* b1    = (const float*)d_in[16];
    const float* W2    = (const float*)d_in[17];
    const float* b2    = (const float*)d_in[18];
    const float* g2    = (const float*)d_in[19];
    const float* be2   = (const float*)d_in[20];
    float* out = (float*)d_out;

    char* ws = (char*)d_ws;
    const int R = B_ * Lq_;  // 80000

    // Workspace (bytes), lifetime-based reuse:
    //  [0,      40.96M)  qb          -> ffno
    //  [40.96M, 81.92M)  sb          -> attno -> h (chunk, 32.77M)
    //  [81.92M,122.88M)  val         -> q1b
    //  [122.88M,204.8M)  oaw(30.7M)+attn(40.96M at 153.6M) -> q1f (81.92M)
    //  [204.8M, ~206.2M) transposed bf16 weights + padded off/aw bias
    u16*  qb    = (u16*)(ws + 0);
    u16*  ffno  = (u16*)(ws + 0);
    u16*  sb    = (u16*)(ws + 40960000);
    u16*  attno = (u16*)(ws + 40960000);
    u16*  h     = (u16*)(ws + 40960000);
    u16*  val   = (u16*)(ws + 81920000);
    u16*  q1b   = (u16*)(ws + 81920000);
    float* oaw  = (float*)(ws + 122880000);
    float* q1f  = (float*)(ws + 122880000);
    u16*  attn  = (u16*)(ws + 153600000);
    u16*  Wv_t  = (u16*)(ws + 204800000);
    u16*  Wo_t  = (u16*)(ws + 204800000 + 131072);
    u16*  W1_t  = (u16*)(ws + 204800000 + 262144);
    u16*  W2_t  = (u16*)(ws + 204800000 + 786432);
    u16*  Woa_t = (u16*)(ws + 204800000 + 1310720);
    float* boa  = (float*)(ws + 204800000 + 1376256);

    const dim3 blk(256);

    // input conversions + weight prep
    cvt_bf16<<<2048, blk, 0, stream>>>(query, qb, R * C_ / 8);
    cvt_bf16<<<2048, blk, 0, stream>>>(src,   sb, R * C_ / 8);
    wprep<<<256,  blk, 0, stream>>>(W_val, Wv_t, 256, 256);
    wprep<<<256,  blk, 0, stream>>>(W_out, Wo_t, 256, 256);
    wprep<<<1024, blk, 0, stream>>>(W1, W1_t, 256, 1024);
    wprep<<<1024, blk, 0, stream>>>(W2, W2_t, 1024, 256);
    prep_offaw<<<128, blk, 0, stream>>>(W_off, W_aw, b_off, b_aw, Woa_t, boa);

    // value = src @ W_val + b_val
    gemm_mfma<false, bf16><<<dim3(2, 625), blk, 0, stream>>>(
        sb, Wv_t, b_val, (bf16*)val, R, 256, 256, 256);
    // oaw = query @ [W_off|W_aw] + bias  (N padded 96->128)
    gemm_mfma<false, float><<<dim3(1, 625), blk, 0, stream>>>(
        qb, Woa_t, boa, oaw, R, 256, 96, 96);
    // bilinear sampling + softmax combine
    sample_attn<<<dim3(R * NH_ / 8), blk, 0, stream>>>(
        (const bf16*)val, oaw, refp, (bf16*)attn);
    // out projection
    gemm_mfma<false, bf16><<<dim3(2, 625), blk, 0, stream>>>(
        attn, Wo_t, b_out, (bf16*)attno, R, 256, 256, 256);
    // q1 = LN(query + attno), also emit bf16 copy for FFN A
    ln_add<<<dim3(R / 4), blk, 0, stream>>>(query, attno, g1, be1, q1f, q1b, R);
    // FFN in 5 chunks of 16000 rows (125 M-tiles each, exact)
    for (int c = 0; c < 5; ++c) {
        const size_t co = (size_t)c * 16000 * C_;
        gemm_mfma<true, bf16><<<dim3(8, 125), blk, 0, stream>>>(
            q1b + co, W1_t, b1, (bf16*)h, 16000, 256, 1024, 1024);
        gemm_mfma<false, bf16><<<dim3(2, 125), blk, 0, stream>>>(
            h, W2_t, b2, (bf16*)(ffno + co), 16000, 1024, 256, 256);
    }
    // out = LN(q1 + ffn)
    ln_add<<<dim3(R / 4), blk, 0, stream>>>(q1f, ffno, g2, be2, out, nullptr, R);
}

// Round 3
// 519.517 us; speedup vs baseline: 4.4229x; 1.3980x over previous
//
#include <hip/hip_runtime.h>
#include <hip/hip_bf16.h>

typedef __hip_bfloat16 bf16;
typedef unsigned short u16;
typedef short short8 __attribute__((ext_vector_type(8)));
typedef float f32x4 __attribute__((ext_vector_type(4)));

static constexpr int B_   = 8;
static constexpr int Lq_  = 10000;
static constexpr int C_   = 256;
static constexpr int NH_  = 8;
static constexpr int NP_  = 4;
static constexpr int DFF_ = 1024;
static constexpr int HIMG = 100;
static constexpr int WIMG = 100;
static constexpr int LIN  = 10000;   // H*W

__device__ __forceinline__ u16 f2bf(float x) {
    union { bf16 b; u16 u; } cv; cv.b = __float2bfloat16(x); return cv.u;
}
__device__ __forceinline__ float bf2f(u16 u) {
    return __uint_as_float((unsigned)u << 16);
}
__device__ __forceinline__ void stf(float* p, float v) { *p = v; }
__device__ __forceinline__ void stf(bf16* p, float v)  { *p = __float2bfloat16(v); }

// Async global -> LDS, 16 B per lane. LDS dest must be wave-uniform base;
// HW writes base + lane*16 (guide §5 caveat m104).
__device__ __forceinline__ void gl_lds16(const void* g, void* l) {
    __builtin_amdgcn_global_load_lds(
        (const __attribute__((address_space(1))) void*)g,
        (__attribute__((address_space(3))) void*)l, 16, 0, 0);
}

// ---------------------------------------------------------------------------
// m97-structure bf16 MFMA GEMM. C[M][ldc] = A[M][K] @ B + bias (opt. ReLU).
// A: [M][K] bf16 row-major. Bt: [Npad][K] bf16 (B transposed), Npad = 128*gridDim.x.
// 256 threads = 4 waves (2x2), 128x128 tile, BK=32, 4x4 16x16x32 frags/wave.
// M must be a multiple of 128; K a multiple of 32. Store guarded by Nreal.
// ---------------------------------------------------------------------------
template <bool RELU, typename TC>
__global__ __launch_bounds__(256) void gemm_mfma(
    const u16* __restrict__ A, const u16* __restrict__ Bt,
    const float* __restrict__ bias, TC* __restrict__ C,
    int M, int K, int Nreal, int ldc)
{
    __shared__ __align__(16) u16 As[128 * 32];
    __shared__ __align__(16) u16 Bs[128 * 32];

    const int tid  = threadIdx.x;
    const int lane = tid & 63;
    const int w    = tid >> 6;
    const int wr   = (w >> 1) * 64;     // wave row offset in tile
    const int wc   = (w & 1) * 64;      // wave col offset in tile
    const int m0   = blockIdx.y * 128;
    const int n0   = blockIdx.x * 128;

    const int srow = lane >> 2;          // 0..15
    const int scol = (lane & 3) << 3;    // element offset 0,8,16,24

    const u16* aG = A  + (size_t)(m0 + w * 32 + srow) * K + scol;
    const u16* bG = Bt + (size_t)(n0 + w * 32 + srow) * K + scol;
    u16* aL0 = &As[(w * 32) * 32];
    u16* aL1 = &As[(w * 32 + 16) * 32];
    u16* bL0 = &Bs[(w * 32) * 32];
    u16* bL1 = &Bs[(w * 32 + 16) * 32];
    const size_t rstep = (size_t)16 * K;

    const char* aR = (const char*)As + (wr + (lane & 15)) * 64 + (lane >> 4) * 16;
    const char* bR = (const char*)Bs + (wc + (lane & 15)) * 64 + (lane >> 4) * 16;

    f32x4 acc[4][4];
#pragma unroll
    for (int i = 0; i < 4; ++i)
#pragma unroll
        for (int j = 0; j < 4; ++j) acc[i][j] = f32x4{0.f, 0.f, 0.f, 0.f};

    for (int k0 = 0; k0 < K; k0 += 32) {
        gl_lds16(aG + k0,         aL0);
        gl_lds16(aG + k0 + rstep, aL1);
        gl_lds16(bG + k0,         bL0);
        gl_lds16(bG + k0 + rstep, bL1);
        __syncthreads();

        short8 af[4], bfr[4];
#pragma unroll
        for (int m = 0; m < 4; ++m) af[m]  = *(const short8*)(aR + m * 16 * 64);
#pragma unroll
        for (int n = 0; n < 4; ++n) bfr[n] = *(const short8*)(bR + n * 16 * 64);
#pragma unroll
        for (int m = 0; m < 4; ++m)
#pragma unroll
            for (int n = 0; n < 4; ++n)
                acc[m][n] = __builtin_amdgcn_mfma_f32_16x16x32_bf16(
                    af[m], bfr[n], acc[m][n], 0, 0, 0);
        __syncthreads();
    }

    // epilogue: C/D layout col = lane&15, row = (lane>>4)*4 + r  (m89/m91)
#pragma unroll
    for (int n = 0; n < 4; ++n) {
        const int gc = n0 + wc + n * 16 + (lane & 15);
        if (gc >= Nreal) continue;
        const float bv = bias[gc];
        const int gr0 = m0 + wr + (lane >> 4) * 4;
#pragma unroll
        for (int m = 0; m < 4; ++m) {
#pragma unroll
            for (int r = 0; r < 4; ++r) {
                float v = acc[m][n][r] + bv;
                if (RELU) v = fmaxf(v, 0.f);
                stf(&C[(size_t)(gr0 + m * 16 + r) * ldc + gc], v);
            }
        }
    }
}

// ---------------------------------------------------------------------------
// f32 -> bf16 bulk convert, 8 elems/thread
// ---------------------------------------------------------------------------
__global__ __launch_bounds__(256) void cvt_bf16(
    const float* __restrict__ in, u16* __restrict__ out, int n8)
{
    for (int i = blockIdx.x * 256 + threadIdx.x; i < n8; i += gridDim.x * 256) {
        const float4 v0 = *(const float4*)(in + (size_t)i * 8);
        const float4 v1 = *(const float4*)(in + (size_t)i * 8 + 4);
        union { short8 s; u16 u[8]; } o;
        o.u[0] = f2bf(v0.x); o.u[1] = f2bf(v0.y); o.u[2] = f2bf(v0.z); o.u[3] = f2bf(v0.w);
        o.u[4] = f2bf(v1.x); o.u[5] = f2bf(v1.y); o.u[6] = f2bf(v1.z); o.u[7] = f2bf(v1.w);
        *(short8*)(out + (size_t)i * 8) = o.s;
    }
}

// transpose+convert weight: Wt[n][k] = bf16(W[k][n]);  Wt is [N][K]
__global__ __launch_bounds__(256) void wprep(
    const float* __restrict__ W, u16* __restrict__ Wt, int K, int N)
{
    const int idx = blockIdx.x * 256 + threadIdx.x;
    if (idx >= N * K) return;
    const int n = idx / K;
    const int k = idx - n * K;
    Wt[idx] = f2bf(W[(size_t)k * N + n]);
}

// combined [W_off | W_aw] -> Wt [128][256] (rows 96..127 zero), bias [128]
__global__ __launch_bounds__(256) void prep_offaw(
    const float* __restrict__ Woff, const float* __restrict__ Waw,
    const float* __restrict__ boff, const float* __restrict__ baw,
    u16* __restrict__ Wt, float* __restrict__ bias)
{
    const int idx = blockIdx.x * 256 + threadIdx.x;   // 128*256 threads
    const int n = idx >> 8, k = idx & 255;
    float v = 0.f;
    if (n < 64)      v = Woff[k * 64 + n];
    else if (n < 96) v = Waw[k * 32 + (n - 64)];
    Wt[idx] = f2bf(v);
    if (idx < 128) bias[idx] = (idx < 64) ? boff[idx] : (idx < 96 ? baw[idx - 64] : 0.f);
}

// ---------------------------------------------------------------------------
// Bilinear sampling + attention-weight combine, v2.
// Lane layout: 4 lanes per (b,q,h) group, 8 channels per lane (16 B gathers).
// 64 groups per 256-thread block; per-group scalar math vectorizes across
// 16 groups/wave (was 2), gather instrs drop 8x (short8 vs scalar bf16).
// ---------------------------------------------------------------------------
__global__ __launch_bounds__(256) void sample_attn(
    const u16* __restrict__ val, const float* __restrict__ oaw,
    const float* __restrict__ refp, u16* __restrict__ attn)
{
    const int t   = threadIdx.x;
    const int gid = blockIdx.x * 64 + (t >> 2);   // (b*Lq+q)*NH + h
    const int c0  = (t & 3) << 3;                 // channel octet within head
    const int h   = gid & (NH_ - 1);
    const int bq  = gid >> 3;                     // grid sized exactly: no guard

    const float* row = oaw + (size_t)bq * 96;
    const float rx = refp[(size_t)bq * 2 + 0] * (float)WIMG;
    const float ry = refp[(size_t)bq * 2 + 1] * (float)HIMG;

    // softmax over NP=4 logits (fast exp: 4-way softmax, precision ample)
    const float4 aw4 = *(const float4*)(row + 64 + h * 4);
    const float mx = fmaxf(fmaxf(aw4.x, aw4.y), fmaxf(aw4.z, aw4.w));
    const float e0 = __expf(aw4.x - mx), e1 = __expf(aw4.y - mx);
    const float e2 = __expf(aw4.z - mx), e3 = __expf(aw4.w - mx);
    const float inv = 1.f / (e0 + e1 + e2 + e3);
    const float w4[4] = {e0 * inv, e1 * inv, e2 * inv, e3 * inv};

    const int b = bq / Lq_;
    const u16* vb = val + (size_t)b * LIN * C_ + h * 32 + c0;

    float acc[8] = {};
#pragma unroll
    for (int p = 0; p < NP_; ++p) {
        const float2 off = *(const float2*)(row + (h * 4 + p) * 2);
        const float x = rx + off.x - 0.5f;
        const float y = ry + off.y - 0.5f;
        const float xf = floorf(x), yf = floorf(y);
        const float lx = x - xf, ly = y - yf;
        const int x0 = (int)xf, y0 = (int)yf;
        const float wp = w4[p];
        const float w00 = wp * (1.f - lx) * (1.f - ly);
        const float w10 = wp * lx * (1.f - ly);
        const float w01 = wp * (1.f - lx) * ly;
        const float w11 = wp * lx * ly;

#pragma unroll
        for (int c = 0; c < 4; ++c) {
            const int xi = x0 + (c & 1);
            const int yi = y0 + (c >> 1);
            const float wc = (c == 0) ? w00 : (c == 1) ? w10 : (c == 2) ? w01 : w11;
            const bool v = ((unsigned)xi < (unsigned)WIMG) & ((unsigned)yi < (unsigned)HIMG);
            const int idx = v ? (yi * WIMG + xi) : 0;     // clamp OOB to 0
            const float w = v ? wc : 0.f;                 // zero its weight
            const short8 d = *(const short8*)(vb + (size_t)idx * C_);
#pragma unroll
            for (int j = 0; j < 8; ++j)
                acc[j] = fmaf(w, bf2f(((const u16*)&d)[j]), acc[j]);
        }
    }

    union { short8 s; u16 u[8]; } o;
#pragma unroll
    for (int j = 0; j < 8; ++j) o.u[j] = f2bf(acc[j]);
    *(short8*)(attn + (size_t)bq * C_ + h * 32 + c0) = o.s;
}

// ---------------------------------------------------------------------------
// Fused residual + LayerNorm; optional secondary bf16 output (next GEMM's A).
// ---------------------------------------------------------------------------
__global__ __launch_bounds__(256) void ln_add(
    const float* __restrict__ x, const u16* __restrict__ y,
    const float* __restrict__ g, const float* __restrict__ be,
    float* __restrict__ out, u16* __restrict__ outb, int rows)
{
    const int row  = blockIdx.x * 4 + (threadIdx.x >> 6);
    const int lane = threadIdx.x & 63;
    if (row >= rows) return;

    const float4 xv = *(const float4*)(x + (size_t)row * C_ + (lane << 2));
    const ushort4 yv = *(const ushort4*)(y + (size_t)row * C_ + (lane << 2));

    float v[4];
    v[0] = xv.x + bf2f(yv.x);
    v[1] = xv.y + bf2f(yv.y);
    v[2] = xv.z + bf2f(yv.z);
    v[3] = xv.w + bf2f(yv.w);

    float s  = v[0] + v[1] + v[2] + v[3];
    float s2 = v[0] * v[0] + v[1] * v[1] + v[2] * v[2] + v[3] * v[3];
#pragma unroll
    for (int o = 32; o >= 1; o >>= 1) {
        s  += __shfl_xor(s, o);
        s2 += __shfl_xor(s2, o);
    }
    const float mean = s * (1.f / 256.f);
    const float var  = fmaxf(s2 * (1.f / 256.f) - mean * mean, 0.f);
    const float rstd = rsqrtf(var + 1e-5f);

    const float4 gv = *(const float4*)(g  + (lane << 2));
    const float4 bv = *(const float4*)(be + (lane << 2));
    float4 o4;
    o4.x = (v[0] - mean) * rstd * gv.x + bv.x;
    o4.y = (v[1] - mean) * rstd * gv.y + bv.y;
    o4.z = (v[2] - mean) * rstd * gv.z + bv.z;
    o4.w = (v[3] - mean) * rstd * gv.w + bv.w;
    *(float4*)(out + (size_t)row * C_ + (lane << 2)) = o4;

    if (outb) {
        ushort4 ob;
        ob.x = f2bf(o4.x); ob.y = f2bf(o4.y); ob.z = f2bf(o4.z); ob.w = f2bf(o4.w);
        *(ushort4*)(outb + (size_t)row * C_ + (lane << 2)) = ob;
    }
}

// ---------------------------------------------------------------------------
extern "C" void kernel_launch(void* const* d_in, const int* in_sizes, int n_in,
                              void* d_out, int out_size, void* d_ws, size_t ws_size,
                              hipStream_t stream)
{
    const float* query = (const float*)d_in[0];
    const float* src   = (const float*)d_in[1];
    const float* refp  = (const float*)d_in[2];
    const float* W_off = (const float*)d_in[5];
    const float* b_off = (const float*)d_in[6];
    const float* W_aw  = (const float*)d_in[7];
    const float* b_aw  = (const float*)d_in[8];
    const float* W_val = (const float*)d_in[9];
    const float* b_val = (const float*)d_in[10];
    const float* W_out = (const float*)d_in[11];
    const float* b_out = (const float*)d_in[12];
    const float* g1    = (const float*)d_in[13];
    const float* be1   = (const float*)d_in[14];
    const float* W1    = (const float*)d_in[15];
    const float* b1    = (const float*)d_in[16];
    const float* W2    = (const float*)d_in[17];
    const float* b2    = (const float*)d_in[18];
    const float* g2    = (const float*)d_in[19];
    const float* be2   = (const float*)d_in[20];
    float* out = (float*)d_out;

    char* ws = (char*)d_ws;
    const int R = B_ * Lq_;  // 80000

    // Workspace (bytes), lifetime-based reuse:
    //  [0,      40.96M)  qb          -> ffno
    //  [40.96M, 81.92M)  sb          -> attno -> h (chunk, 32.77M)
    //  [81.92M,122.88M)  val         -> q1b
    //  [122.88M,204.8M)  oaw(30.7M)+attn(40.96M at 153.6M) -> q1f (81.92M)
    //  [204.8M, ~206.2M) transposed bf16 weights + padded off/aw bias
    u16*  qb    = (u16*)(ws + 0);
    u16*  ffno  = (u16*)(ws + 0);
    u16*  sb    = (u16*)(ws + 40960000);
    u16*  attno = (u16*)(ws + 40960000);
    u16*  h     = (u16*)(ws + 40960000);
    u16*  val   = (u16*)(ws + 81920000);
    u16*  q1b   = (u16*)(ws + 81920000);
    float* oaw  = (float*)(ws + 122880000);
    float* q1f  = (float*)(ws + 122880000);
    u16*  attn  = (u16*)(ws + 153600000);
    u16*  Wv_t  = (u16*)(ws + 204800000);
    u16*  Wo_t  = (u16*)(ws + 204800000 + 131072);
    u16*  W1_t  = (u16*)(ws + 204800000 + 262144);
    u16*  W2_t  = (u16*)(ws + 204800000 + 786432);
    u16*  Woa_t = (u16*)(ws + 204800000 + 1310720);
    float* boa  = (float*)(ws + 204800000 + 1376256);

    const dim3 blk(256);

    // input conversions + weight prep
    cvt_bf16<<<2048, blk, 0, stream>>>(query, qb, R * C_ / 8);
    cvt_bf16<<<2048, blk, 0, stream>>>(src,   sb, R * C_ / 8);
    wprep<<<256,  blk, 0, stream>>>(W_val, Wv_t, 256, 256);
    wprep<<<256,  blk, 0, stream>>>(W_out, Wo_t, 256, 256);
    wprep<<<1024, blk, 0, stream>>>(W1, W1_t, 256, 1024);
    wprep<<<1024, blk, 0, stream>>>(W2, W2_t, 1024, 256);
    prep_offaw<<<128, blk, 0, stream>>>(W_off, W_aw, b_off, b_aw, Woa_t, boa);

    // value = src @ W_val + b_val
    gemm_mfma<false, bf16><<<dim3(2, 625), blk, 0, stream>>>(
        sb, Wv_t, b_val, (bf16*)val, R, 256, 256, 256);
    // oaw = query @ [W_off|W_aw] + bias  (N padded 96->128)
    gemm_mfma<false, float><<<dim3(1, 625), blk, 0, stream>>>(
        qb, Woa_t, boa, oaw, R, 256, 96, 96);
    // bilinear sampling + softmax combine (64 groups / block, 4 lanes each)
    sample_attn<<<dim3(R * NH_ / 64), blk, 0, stream>>>(val, oaw, refp, attn);
    // out projection
    gemm_mfma<false, bf16><<<dim3(2, 625), blk, 0, stream>>>(
        attn, Wo_t, b_out, (bf16*)attno, R, 256, 256, 256);
    // q1 = LN(query + attno), also emit bf16 copy for FFN A
    ln_add<<<dim3(R / 4), blk, 0, stream>>>(query, attno, g1, be1, q1f, q1b, R);
    // FFN in 5 chunks of 16000 rows (125 M-tiles each, exact)
    for (int c = 0; c < 5; ++c) {
        const size_t co = (size_t)c * 16000 * C_;
        gemm_mfma<true, bf16><<<dim3(8, 125), blk, 0, stream>>>(
            q1b + co, W1_t, b1, (bf16*)h, 16000, 256, 1024, 1024);
        gemm_mfma<false, bf16><<<dim3(2, 125), blk, 0, stream>>>(
            h, W2_t, b2, (bf16*)(ffno + co), 16000, 1024, 256, 256);
    }
    // out = LN(q1 + ffn)
    ln_add<<<dim3(R / 4), blk, 0, stream>>>(q1f, ffno, g2, be2, out, nullptr, R);
}

// Round 4
// 368.734 us; speedup vs baseline: 6.2315x; 1.4089x over previous
//
#include <hip/hip_runtime.h>
#include <hip/hip_bf16.h>

typedef __hip_bfloat16 bf16;
typedef unsigned short u16;
typedef short short8 __attribute__((ext_vector_type(8)));
typedef float f32x4 __attribute__((ext_vector_type(4)));

static constexpr int B_   = 8;
static constexpr int Lq_  = 10000;
static constexpr int C_   = 256;
static constexpr int NH_  = 8;
static constexpr int NP_  = 4;
static constexpr int DFF_ = 1024;
static constexpr int HIMG = 100;
static constexpr int WIMG = 100;
static constexpr int LIN  = 10000;   // H*W

__device__ __forceinline__ u16 f2bf(float x) {
    union { bf16 b; u16 u; } cv; cv.b = __float2bfloat16(x); return cv.u;
}
__device__ __forceinline__ float bf2f(u16 u) {
    return __uint_as_float((unsigned)u << 16);
}
__device__ __forceinline__ void stf(float* p, float v) { *p = v; }
__device__ __forceinline__ void stf(u16* p, float v)   { *p = f2bf(v); }

// Async global -> LDS, 16 B per lane. LDS dest is wave-uniform base;
// HW writes base + lane*16 (guide §5 m104).
__device__ __forceinline__ void gl_lds16(const void* g, void* l) {
    __builtin_amdgcn_global_load_lds(
        (const __attribute__((address_space(1))) void*)g,
        (__attribute__((address_space(3))) void*)l, 16, 0, 0);
}

// ---------------------------------------------------------------------------
// bf16 MFMA GEMM, 128x128 tile, BK=32, 4 waves, T3-minimum 2-phase pipeline:
//   prologue: STAGE(0); vmcnt(0); barrier
//   iter t:   STAGE(t+1) -> buf^1; compute(t) from buf; vmcnt(0)+lgkmcnt(0);
//             s_barrier        (loads of t+1 hide under compute(t))
// AF32: A is f32 in global, converted in-kernel during staging (reg->LDS).
// M, K multiples of 128/32. Store guarded by Nreal only.
// ---------------------------------------------------------------------------
template <bool RELU, bool AF32, typename TC>
__global__ __launch_bounds__(256) void gemm_mfma(
    const void* __restrict__ Av, const u16* __restrict__ Bt,
    const float* __restrict__ bias, TC* __restrict__ C,
    int M, int K, int Nreal, int ldc)
{
    __shared__ __align__(16) u16 As[2][128 * 32];
    __shared__ __align__(16) u16 Bs[2][128 * 32];

    const int tid  = threadIdx.x;
    const int lane = tid & 63;
    const int w    = tid >> 6;
    const int wr   = (w >> 1) * 64;
    const int wc   = (w & 1) * 64;
    const int m0   = blockIdx.y * 128;
    const int n0   = blockIdx.x * 128;

    // gl_lds staging geometry: wave w stages rows [w*32, w*32+32); the DMA
    // writes lane*16B at the uniform base -> lane covers row (lane>>2),
    // 16B chunk (lane&3) of the 64B row.
    const int srow = lane >> 2;
    const int scol = (lane & 3) << 3;
    const u16* bG = Bt + (size_t)(n0 + w * 32 + srow) * K + scol;
    const size_t rstep16 = (size_t)16 * K;

    // A staging source
    const u16*   aG  = nullptr;
    const float* aGf = nullptr;
    int ar = 0, ac = 0;
    if constexpr (AF32) {
        ar  = lane >> 3;          // row within 8-row rep group
        ac  = (lane & 7) << 2;    // f32 col (0..28, step 4)
        aGf = (const float*)Av + (size_t)(m0 + w * 32 + ar) * K + ac;
    } else {
        aG = (const u16*)Av + (size_t)(m0 + w * 32 + srow) * K + scol;
    }

    // fragment read offsets (elements) in [128][32] row-major LDS
    const int aRoff = (wr + (lane & 15)) * 32 + (lane >> 4) * 8;
    const int bRoff = (wc + (lane & 15)) * 32 + (lane >> 4) * 8;

    f32x4 acc[4][4];
#pragma unroll
    for (int i = 0; i < 4; ++i)
#pragma unroll
        for (int j = 0; j < 4; ++j) acc[i][j] = f32x4{0.f, 0.f, 0.f, 0.f};

    float4 a4[4];   // reg-staged A (AF32 path)

    const int nt = K >> 5;

    // ---- prologue: stage tile 0 into buf 0
    if constexpr (AF32) {
#pragma unroll
        for (int rep = 0; rep < 4; ++rep)
            a4[rep] = *(const float4*)(aGf + (size_t)(rep * 8) * K);
#pragma unroll
        for (int rep = 0; rep < 4; ++rep) {
            ushort4 v{f2bf(a4[rep].x), f2bf(a4[rep].y), f2bf(a4[rep].z), f2bf(a4[rep].w)};
            *(ushort4*)&As[0][(w * 32 + rep * 8 + ar) * 32 + ac] = v;
        }
    } else {
        gl_lds16(aG, &As[0][(w * 32) * 32]);
        gl_lds16(aG + rstep16, &As[0][(w * 32 + 16) * 32]);
    }
    gl_lds16(bG, &Bs[0][(w * 32) * 32]);
    gl_lds16(bG + rstep16, &Bs[0][(w * 32 + 16) * 32]);
    asm volatile("s_waitcnt vmcnt(0) lgkmcnt(0)" ::: "memory");
    __builtin_amdgcn_s_barrier();

    for (int t = 0; t < nt; ++t) {
        const int cur = t & 1;
        const int nxt = cur ^ 1;
        const int k0n = (t + 1) << 5;
        const bool has_next = (t + 1 < nt);

        // ---- issue next-tile staging (overlaps with compute below)
        if (has_next) {
            if constexpr (AF32) {
#pragma unroll
                for (int rep = 0; rep < 4; ++rep)
                    a4[rep] = *(const float4*)(aGf + k0n + (size_t)(rep * 8) * K);
            } else {
                gl_lds16(aG + k0n, &As[nxt][(w * 32) * 32]);
                gl_lds16(aG + k0n + rstep16, &As[nxt][(w * 32 + 16) * 32]);
            }
            gl_lds16(bG + k0n, &Bs[nxt][(w * 32) * 32]);
            gl_lds16(bG + k0n + rstep16, &Bs[nxt][(w * 32 + 16) * 32]);
        }

        // ---- compute current tile
        short8 af[4], bfr[4];
#pragma unroll
        for (int m = 0; m < 4; ++m) af[m]  = *(const short8*)&As[cur][aRoff + m * 16 * 32];
#pragma unroll
        for (int n = 0; n < 4; ++n) bfr[n] = *(const short8*)&Bs[cur][bRoff + n * 16 * 32];
#pragma unroll
        for (int m = 0; m < 4; ++m)
#pragma unroll
            for (int n = 0; n < 4; ++n)
                acc[m][n] = __builtin_amdgcn_mfma_f32_16x16x32_bf16(
                    af[m], bfr[n], acc[m][n], 0, 0, 0);

        // AF32: write converted next-tile A into LDS after compute
        if constexpr (AF32) {
            if (has_next) {
#pragma unroll
                for (int rep = 0; rep < 4; ++rep) {
                    ushort4 v{f2bf(a4[rep].x), f2bf(a4[rep].y), f2bf(a4[rep].z), f2bf(a4[rep].w)};
                    *(ushort4*)&As[nxt][(w * 32 + rep * 8 + ar) * 32 + ac] = v;
                }
            }
        }

        asm volatile("s_waitcnt vmcnt(0) lgkmcnt(0)" ::: "memory");
        __builtin_amdgcn_s_barrier();
    }

    // ---- epilogue: C/D layout col = lane&15, row = (lane>>4)*4 + r (m89/m91)
#pragma unroll
    for (int n = 0; n < 4; ++n) {
        const int gc = n0 + wc + n * 16 + (lane & 15);
        if (gc >= Nreal) continue;
        const float bv = bias[gc];
        const int gr0 = m0 + wr + (lane >> 4) * 4;
#pragma unroll
        for (int m = 0; m < 4; ++m) {
#pragma unroll
            for (int r = 0; r < 4; ++r) {
                float v = acc[m][n][r] + bv;
                if (RELU) v = fmaxf(v, 0.f);
                stf(&C[(size_t)(gr0 + m * 16 + r) * ldc + gc], v);
            }
        }
    }
}

// ---------------------------------------------------------------------------
// One-shot weight prep: transpose+convert all weights, build padded off/aw.
// Segments: Wv_t 65536 | Wo_t 65536 | W1_t 262144 | W2_t 262144 | Woa_t 32768
//           | boa 128   (total 688256 items)
// ---------------------------------------------------------------------------
__global__ __launch_bounds__(256) void prep_all(
    const float* __restrict__ Wv, const float* __restrict__ Wo,
    const float* __restrict__ W1, const float* __restrict__ W2,
    const float* __restrict__ Woff, const float* __restrict__ Waw,
    const float* __restrict__ boff, const float* __restrict__ baw,
    u16* __restrict__ Wv_t, u16* __restrict__ Wo_t,
    u16* __restrict__ W1_t, u16* __restrict__ W2_t,
    u16* __restrict__ Woa_t, float* __restrict__ boa)
{
    const int idx = blockIdx.x * 256 + threadIdx.x;
    if (idx < 65536) {                       // Wv [256][256] -> [n][k]
        const int n = idx >> 8, k = idx & 255;
        Wv_t[idx] = f2bf(Wv[(size_t)k * 256 + n]);
    } else if (idx < 131072) {               // Wo [256][256]
        const int i = idx - 65536, n = i >> 8, k = i & 255;
        Wo_t[i] = f2bf(Wo[(size_t)k * 256 + n]);
    } else if (idx < 393216) {               // W1 [256][1024] -> [1024][256]
        const int i = idx - 131072, n = i >> 8, k = i & 255;
        W1_t[i] = f2bf(W1[(size_t)k * 1024 + n]);
    } else if (idx < 655360) {               // W2 [1024][256] -> [256][1024]
        const int i = idx - 393216, n = i >> 10, k = i & 1023;
        W2_t[i] = f2bf(W2[(size_t)k * 256 + n]);
    } else if (idx < 688128) {               // [W_off|W_aw] -> [128][256], pad 0
        const int i = idx - 655360, n = i >> 8, k = i & 255;
        float v = 0.f;
        if (n < 64)      v = Woff[(size_t)k * 64 + n];
        else if (n < 96) v = Waw[(size_t)k * 32 + (n - 64)];
        Woa_t[i] = f2bf(v);
    } else if (idx < 688256) {
        const int i = idx - 688128;
        boa[i] = (i < 64) ? boff[i] : (i < 96 ? baw[i - 64] : 0.f);
    }
}

// ---------------------------------------------------------------------------
// Bilinear sampling + attention-weight combine (R3 layout: 4 lanes/group,
// 8 channels/lane, 16 B gathers).
// ---------------------------------------------------------------------------
__global__ __launch_bounds__(256) void sample_attn(
    const u16* __restrict__ val, const float* __restrict__ oaw,
    const float* __restrict__ refp, u16* __restrict__ attn)
{
    const int t   = threadIdx.x;
    const int gid = blockIdx.x * 64 + (t >> 2);   // (b*Lq+q)*NH + h
    const int c0  = (t & 3) << 3;
    const int h   = gid & (NH_ - 1);
    const int bq  = gid >> 3;

    const float* row = oaw + (size_t)bq * 96;
    const float rx = refp[(size_t)bq * 2 + 0] * (float)WIMG;
    const float ry = refp[(size_t)bq * 2 + 1] * (float)HIMG;

    const float4 aw4 = *(const float4*)(row + 64 + h * 4);
    const float mx = fmaxf(fmaxf(aw4.x, aw4.y), fmaxf(aw4.z, aw4.w));
    const float e0 = __expf(aw4.x - mx), e1 = __expf(aw4.y - mx);
    const float e2 = __expf(aw4.z - mx), e3 = __expf(aw4.w - mx);
    const float inv = 1.f / (e0 + e1 + e2 + e3);
    const float w4[4] = {e0 * inv, e1 * inv, e2 * inv, e3 * inv};

    const int b = bq / Lq_;
    const u16* vb = val + (size_t)b * LIN * C_ + h * 32 + c0;

    float acc[8] = {};
#pragma unroll
    for (int p = 0; p < NP_; ++p) {
        const float2 off = *(const float2*)(row + (h * 4 + p) * 2);
        const float x = rx + off.x - 0.5f;
        const float y = ry + off.y - 0.5f;
        const float xf = floorf(x), yf = floorf(y);
        const float lx = x - xf, ly = y - yf;
        const int x0 = (int)xf, y0 = (int)yf;
        const float wp = w4[p];
        const float w00 = wp * (1.f - lx) * (1.f - ly);
        const float w10 = wp * lx * (1.f - ly);
        const float w01 = wp * (1.f - lx) * ly;
        const float w11 = wp * lx * ly;

#pragma unroll
        for (int c = 0; c < 4; ++c) {
            const int xi = x0 + (c & 1);
            const int yi = y0 + (c >> 1);
            const float wc = (c == 0) ? w00 : (c == 1) ? w10 : (c == 2) ? w01 : w11;
            const bool v = ((unsigned)xi < (unsigned)WIMG) & ((unsigned)yi < (unsigned)HIMG);
            const int idx = v ? (yi * WIMG + xi) : 0;
            const float w = v ? wc : 0.f;
            const short8 d = *(const short8*)(vb + (size_t)idx * C_);
#pragma unroll
            for (int j = 0; j < 8; ++j)
                acc[j] = fmaf(w, bf2f(((const u16*)&d)[j]), acc[j]);
        }
    }

    union { short8 s; u16 u[8]; } o;
#pragma unroll
    for (int j = 0; j < 8; ++j) o.u[j] = f2bf(acc[j]);
    *(short8*)(attn + (size_t)bq * C_ + h * 32 + c0) = o.s;
}

// ---------------------------------------------------------------------------
// Fused residual + LayerNorm. XF32: x dtype. OUTF32: output dtype.
// ---------------------------------------------------------------------------
template <bool XF32, bool OUTF32>
__global__ __launch_bounds__(256) void ln_add(
    const void* __restrict__ xp, const u16* __restrict__ y,
    const float* __restrict__ g, const float* __restrict__ be,
    void* __restrict__ outp, int rows)
{
    const int row  = blockIdx.x * 4 + (threadIdx.x >> 6);
    const int lane = threadIdx.x & 63;
    if (row >= rows) return;

    float v[4];
    if constexpr (XF32) {
        const float4 xv = *(const float4*)((const float*)xp + (size_t)row * C_ + (lane << 2));
        v[0] = xv.x; v[1] = xv.y; v[2] = xv.z; v[3] = xv.w;
    } else {
        const ushort4 xv = *(const ushort4*)((const u16*)xp + (size_t)row * C_ + (lane << 2));
        v[0] = bf2f(xv.x); v[1] = bf2f(xv.y); v[2] = bf2f(xv.z); v[3] = bf2f(xv.w);
    }
    const ushort4 yv = *(const ushort4*)(y + (size_t)row * C_ + (lane << 2));
    v[0] += bf2f(yv.x); v[1] += bf2f(yv.y); v[2] += bf2f(yv.z); v[3] += bf2f(yv.w);

    float s  = v[0] + v[1] + v[2] + v[3];
    float s2 = v[0] * v[0] + v[1] * v[1] + v[2] * v[2] + v[3] * v[3];
#pragma unroll
    for (int o = 32; o >= 1; o >>= 1) {
        s  += __shfl_xor(s, o);
        s2 += __shfl_xor(s2, o);
    }
    const float mean = s * (1.f / 256.f);
    const float var  = fmaxf(s2 * (1.f / 256.f) - mean * mean, 0.f);
    const float rstd = rsqrtf(var + 1e-5f);

    const float4 gv = *(const float4*)(g  + (lane << 2));
    const float4 bv = *(const float4*)(be + (lane << 2));
    float o4[4];
    o4[0] = (v[0] - mean) * rstd * gv.x + bv.x;
    o4[1] = (v[1] - mean) * rstd * gv.y + bv.y;
    o4[2] = (v[2] - mean) * rstd * gv.z + bv.z;
    o4[3] = (v[3] - mean) * rstd * gv.w + bv.w;

    if constexpr (OUTF32) {
        float4 ov{o4[0], o4[1], o4[2], o4[3]};
        *(float4*)((float*)outp + (size_t)row * C_ + (lane << 2)) = ov;
    } else {
        ushort4 ov{f2bf(o4[0]), f2bf(o4[1]), f2bf(o4[2]), f2bf(o4[3])};
        *(ushort4*)((u16*)outp + (size_t)row * C_ + (lane << 2)) = ov;
    }
}

// ---------------------------------------------------------------------------
extern "C" void kernel_launch(void* const* d_in, const int* in_sizes, int n_in,
                              void* d_out, int out_size, void* d_ws, size_t ws_size,
                              hipStream_t stream)
{
    const float* query = (const float*)d_in[0];
    const float* src   = (const float*)d_in[1];
    const float* refp  = (const float*)d_in[2];
    const float* W_off = (const float*)d_in[5];
    const float* b_off = (const float*)d_in[6];
    const float* W_aw  = (const float*)d_in[7];
    const float* b_aw  = (const float*)d_in[8];
    const float* W_val = (const float*)d_in[9];
    const float* b_val = (const float*)d_in[10];
    const float* W_out = (const float*)d_in[11];
    const float* b_out = (const float*)d_in[12];
    const float* g1    = (const float*)d_in[13];
    const float* be1   = (const float*)d_in[14];
    const float* W1    = (const float*)d_in[15];
    const float* b1    = (const float*)d_in[16];
    const float* W2    = (const float*)d_in[17];
    const float* b2    = (const float*)d_in[18];
    const float* g2    = (const float*)d_in[19];
    const float* be2   = (const float*)d_in[20];
    float* out = (float*)d_out;

    char* ws = (char*)d_ws;
    const int R = B_ * Lq_;  // 80000

    // Workspace layout (ws_size ~327.7MB observed; we use ~247.1MB):
    //  [0, 40.96M)        val bf16            -> ffno bf16
    //  [40.96M, 204.8M)   oaw f32 (30.72M) | attn (40.96M @71.68M)
    //                     | attno (40.96M @112.64M)   -> h bf16 (163.84M)
    //  [204.8M, 245.76M)  q1b bf16
    //  [245.76M, ~247.1M) transposed bf16 weights + padded bias
    u16*  val   = (u16*)(ws + 0);
    u16*  ffno  = (u16*)(ws + 0);
    float* oaw  = (float*)(ws + 40960000);
    u16*  h     = (u16*)(ws + 40960000);
    u16*  attn  = (u16*)(ws + 71680000);
    u16*  attno = (u16*)(ws + 112640000);
    u16*  q1b   = (u16*)(ws + 204800000);
    u16*  Wv_t  = (u16*)(ws + 245760000);
    u16*  Wo_t  = (u16*)(ws + 245760000 + 131072);
    u16*  W1_t  = (u16*)(ws + 245760000 + 262144);
    u16*  W2_t  = (u16*)(ws + 245760000 + 786432);
    u16*  Woa_t = (u16*)(ws + 245760000 + 1310720);
    float* boa  = (float*)(ws + 245760000 + 1376256);

    const dim3 blk(256);

    // weight prep (one kernel)
    prep_all<<<2689, blk, 0, stream>>>(W_val, W_out, W1, W2, W_off, W_aw,
                                       b_off, b_aw, Wv_t, Wo_t, W1_t, W2_t,
                                       Woa_t, boa);

    // value = src @ W_val + b_val   (A f32, converted in-kernel)
    gemm_mfma<false, true, u16><<<dim3(2, 625), blk, 0, stream>>>(
        src, Wv_t, b_val, val, R, 256, 256, 256);
    // oaw = query @ [W_off|W_aw] + bias  (N padded 96->128)
    gemm_mfma<false, true, float><<<dim3(1, 625), blk, 0, stream>>>(
        query, Woa_t, boa, oaw, R, 256, 96, 96);
    // bilinear sampling + softmax combine
    sample_attn<<<dim3(R * NH_ / 64), blk, 0, stream>>>(val, oaw, refp, attn);
    // out projection
    gemm_mfma<false, false, u16><<<dim3(2, 625), blk, 0, stream>>>(
        attn, Wo_t, b_out, attno, R, 256, 256, 256);
    // q1 = LN(query + attno) -> bf16
    ln_add<true, false><<<dim3(R / 4), blk, 0, stream>>>(
        query, attno, g1, be1, q1b, R);
    // FFN single-shot: h = relu(q1b@W1+b1); ffno = h@W2+b2
    gemm_mfma<true, false, u16><<<dim3(8, 625), blk, 0, stream>>>(
        q1b, W1_t, b1, h, R, 256, 1024, 1024);
    gemm_mfma<false, false, u16><<<dim3(2, 625), blk, 0, stream>>>(
        h, W2_t, b2, ffno, R, 1024, 256, 256);
    // out = LN(q1 + ffn) -> f32
    ln_add<false, true><<<dim3(R / 4), blk, 0, stream>>>(
        q1b, ffno, g2, be2, out, R);
}

// Round 5
// 327.447 us; speedup vs baseline: 7.0172x; 1.1261x over previous
//
#include <hip/hip_runtime.h>
#include <hip/hip_bf16.h>

typedef __hip_bfloat16 bf16;
typedef unsigned short u16;
typedef short short8 __attribute__((ext_vector_type(8)));
typedef float f32x4 __attribute__((ext_vector_type(4)));

static constexpr int B_   = 8;
static constexpr int Lq_  = 10000;
static constexpr int C_   = 256;
static constexpr int NH_  = 8;
static constexpr int NP_  = 4;
static constexpr int HIMG = 100;
static constexpr int WIMG = 100;
static constexpr int LIN  = 10000;   // H*W

__device__ __forceinline__ u16 f2bf(float x) {
    union { bf16 b; u16 u; } cv; cv.b = __float2bfloat16(x); return cv.u;
}
__device__ __forceinline__ float bf2f(u16 u) {
    return __uint_as_float((unsigned)u << 16);
}

// Async global -> LDS, 16 B per lane. LDS dest wave-uniform; HW writes
// base + lane*16 (guide §5 m104).
__device__ __forceinline__ void gl_lds16(const void* g, void* l) {
    __builtin_amdgcn_global_load_lds(
        (const __attribute__((address_space(1))) void*)g,
        (__attribute__((address_space(3))) void*)l, 16, 0, 0);
}
__device__ __forceinline__ void drain_barrier() {
    asm volatile("s_waitcnt vmcnt(0) lgkmcnt(0)" ::: "memory");
    __builtin_amdgcn_s_barrier();
}

// Swizzle convention (rule #21, both-sides-or-neither):
//   storage[row][e] = logical[row][e ^ ((row&S)<<3)]   (granule = 8 elem = 16B)
//   S=7 for >=128B rows, S=3 for 64B rows. Stagers copy storage linearly;
//   readers XOR the same pattern.

// ---------------------------------------------------------------------------
// gemm256: C[M][256] = A[M][K] @ B + bias, tile 128x256, 8 waves (2m x 4n),
// BK=64, 2-phase dbuf staging. B pre-swizzled [256][K] (S=7 per 64-elem slice).
// AF32: A is f32, reg-staged+converted; else bf16, gl_lds w/ source swizzle.
// LN: epilogue += resid (f32), row-LayerNorm(g,be), write u16 SWIZZLED (S=7).
// else: plain bias epilogue, write u16 linear.
// ---------------------------------------------------------------------------
template <bool AF32, bool LN>
__global__ __launch_bounds__(512, 2) void gemm256(
    const void* __restrict__ Av, const u16* __restrict__ Bg,
    const float* __restrict__ bias, const float* __restrict__ resid,
    const float* __restrict__ gw, const float* __restrict__ bw,
    u16* __restrict__ Co, int K)
{
    __shared__ __align__(16) u16 At[2][128 * 64];
    __shared__ __align__(16) u16 Bt[2][256 * 64];
    __shared__ float red[2][128][4];

    const int tid  = threadIdx.x;
    const int lane = tid & 63;
    const int w    = tid >> 6;
    const int wm   = w >> 2, wn = w & 3;
    const int m0   = blockIdx.x * 128;

    f32x4 acc[4][4];
#pragma unroll
    for (int i = 0; i < 4; ++i)
#pragma unroll
        for (int j = 0; j < 4; ++j) acc[i][j] = f32x4{0.f, 0.f, 0.f, 0.f};

    auto stageA = [&](int t) {
        const int kt = t << 6;
        if constexpr (AF32) {
            const int row = tid >> 2;
            const int k0  = (tid & 3) << 4;
            const float* s = (const float*)Av + (size_t)(m0 + row) * K + kt + k0;
            float4 v0 = *(const float4*)(s + 0);
            float4 v1 = *(const float4*)(s + 4);
            float4 v2 = *(const float4*)(s + 8);
            float4 v3 = *(const float4*)(s + 12);
            union { short8 s8; u16 u[8]; } ga, gb;
            ga.u[0]=f2bf(v0.x); ga.u[1]=f2bf(v0.y); ga.u[2]=f2bf(v0.z); ga.u[3]=f2bf(v0.w);
            ga.u[4]=f2bf(v1.x); ga.u[5]=f2bf(v1.y); ga.u[6]=f2bf(v1.z); ga.u[7]=f2bf(v1.w);
            gb.u[0]=f2bf(v2.x); gb.u[1]=f2bf(v2.y); gb.u[2]=f2bf(v2.z); gb.u[3]=f2bf(v2.w);
            gb.u[4]=f2bf(v3.x); gb.u[5]=f2bf(v3.y); gb.u[6]=f2bf(v3.z); gb.u[7]=f2bf(v3.w);
            u16* d = &At[t & 1][row * 64];
            *(short8*)&d[(k0)     ^ ((row & 7) << 3)] = ga.s8;
            *(short8*)&d[(k0 + 8) ^ ((row & 7) << 3)] = gb.s8;
        } else {
#pragma unroll
            for (int i = 0; i < 2; ++i) {
                const int rb  = w * 16 + i * 8;
                const int row = rb + (lane >> 3);
                const int gs  = (lane & 7) ^ (row & 7);
                gl_lds16((const u16*)Av + (size_t)(m0 + row) * K + kt + gs * 8,
                         &At[t & 1][rb * 64]);
            }
        }
    };
    auto stageB = [&](int t) {
        const int kt = t << 6;
#pragma unroll
        for (int i = 0; i < 4; ++i) {
            const int rb  = w * 32 + i * 8;
            const int row = rb + (lane >> 3);
            gl_lds16(Bg + (size_t)row * K + kt + (lane & 7) * 8,
                     &Bt[t & 1][rb * 64]);
        }
    };
    auto compute = [&](int t) {
        const u16* a = At[t & 1];
        const u16* b = Bt[t & 1];
#pragma unroll
        for (int ks = 0; ks < 2; ++ks) {
            const int ko = ks * 32 + ((lane >> 4) << 3);
            short8 bfr[4];
#pragma unroll
            for (int n = 0; n < 4; ++n) {
                const int nr = wn * 64 + n * 16 + (lane & 15);
                bfr[n] = *(const short8*)&b[nr * 64 + (ko ^ ((nr & 7) << 3))];
            }
#pragma unroll
            for (int m = 0; m < 4; ++m) {
                const int ar = wm * 64 + m * 16 + (lane & 15);
                const short8 af = *(const short8*)&a[ar * 64 + (ko ^ ((ar & 7) << 3))];
#pragma unroll
                for (int n = 0; n < 4; ++n)
                    acc[m][n] = __builtin_amdgcn_mfma_f32_16x16x32_bf16(
                        af, bfr[n], acc[m][n], 0, 0, 0);
            }
        }
    };

    stageA(0); stageB(0);
    drain_barrier();
    const int nt = K >> 6;
    for (int t = 0; t < nt; ++t) {
        if (t + 1 < nt) { stageA(t + 1); stageB(t + 1); }
        compute(t);
        drain_barrier();
    }

    // epilogue. C/D frag: col = lane&15 (+n*16+wn*64), row = (lane>>4)*4+r (+m*16+wm*64)
    float bcol[4], gcol[4], becol[4];
#pragma unroll
    for (int n = 0; n < 4; ++n) {
        const int col = wn * 64 + n * 16 + (lane & 15);
        bcol[n] = bias[col];
        if (LN) { gcol[n] = gw[col]; becol[n] = bw[col]; }
    }

    if constexpr (!LN) {
#pragma unroll
        for (int m = 0; m < 4; ++m)
#pragma unroll
            for (int r = 0; r < 4; ++r) {
                const int lr = wm * 64 + m * 16 + (lane >> 4) * 4 + r;
#pragma unroll
                for (int n = 0; n < 4; ++n) {
                    const int col = wn * 64 + n * 16 + (lane & 15);
                    Co[(size_t)(m0 + lr) * 256 + col] = f2bf(acc[m][n][r] + bcol[n]);
                }
            }
    } else {
        // v = acc + bias + resid; in-place into acc
        float s[4][4], s2[4][4];
#pragma unroll
        for (int m = 0; m < 4; ++m)
#pragma unroll
            for (int r = 0; r < 4; ++r) {
                const int lr = wm * 64 + m * 16 + (lane >> 4) * 4 + r;
                float ps = 0.f, ps2 = 0.f;
#pragma unroll
                for (int n = 0; n < 4; ++n) {
                    const int col = wn * 64 + n * 16 + (lane & 15);
                    float v = acc[m][n][r] + bcol[n]
                            + resid[(size_t)(m0 + lr) * 256 + col];
                    acc[m][n][r] = v;
                    ps += v; ps2 += v * v;
                }
#pragma unroll
                for (int o = 1; o < 16; o <<= 1) {
                    ps  += __shfl_xor(ps,  o);
                    ps2 += __shfl_xor(ps2, o);
                }
                s[m][r] = ps; s2[m][r] = ps2;
            }
        if ((lane & 15) == 0) {
#pragma unroll
            for (int m = 0; m < 4; ++m)
#pragma unroll
                for (int r = 0; r < 4; ++r) {
                    const int lr = wm * 64 + m * 16 + (lane >> 4) * 4 + r;
                    red[0][lr][wn] = s[m][r];
                    red[1][lr][wn] = s2[m][r];
                }
        }
        __syncthreads();
        if (tid < 128) {
            const float ss  = red[0][tid][0] + red[0][tid][1] + red[0][tid][2] + red[0][tid][3];
            const float ss2 = red[1][tid][0] + red[1][tid][1] + red[1][tid][2] + red[1][tid][3];
            const float mean = ss * (1.f / 256.f);
            const float var  = fmaxf(ss2 * (1.f / 256.f) - mean * mean, 0.f);
            red[0][tid][0] = mean;
            red[1][tid][0] = rsqrtf(var + 1e-5f);
        }
        __syncthreads();
#pragma unroll
        for (int m = 0; m < 4; ++m)
#pragma unroll
            for (int r = 0; r < 4; ++r) {
                const int lr = wm * 64 + m * 16 + (lane >> 4) * 4 + r;
                const float mean = red[0][lr][0];
                const float rstd = red[1][lr][0];
#pragma unroll
                for (int n = 0; n < 4; ++n) {
                    const int col = wn * 64 + n * 16 + (lane & 15);
                    const float o = (acc[m][n][r] - mean) * rstd * gcol[n] + becol[n];
                    // swizzled store (q1b layout, S=7 over 256-elem rows)
                    Co[(size_t)(m0 + lr) * 256 + (col ^ ((lr & 7) << 3))] = f2bf(o);
                }
            }
    }
}

// ---------------------------------------------------------------------------
// ffn_fused: per 128-row block: As = q1b tile resident (LDS, swizzled);
// 8 chunks of DFF=128: h = relu(As@W1c+b1c) -> Hs (LDS); acc2 += Hs@W2c.
// Epilogue: LN2(q1 + acc2 + b2) -> out f32. h NEVER touches HBM.
// ---------------------------------------------------------------------------
__global__ __launch_bounds__(512, 2) void ffn_fused(
    const u16* __restrict__ q1b, const u16* __restrict__ W1s,
    const u16* __restrict__ W2s, const float* __restrict__ b1,
    const float* __restrict__ b2, const float* __restrict__ g2,
    const float* __restrict__ be2, float* __restrict__ out)
{
    __shared__ __align__(16) u16 As[128 * 256];      // 64 KB, resident
    __shared__ __align__(16) u16 Hs[128 * 128];      // 32 KB
    __shared__ __align__(16) u16 B1t[2][128 * 32];   // 16 KB
    __shared__ __align__(16) u16 B2t[2][256 * 32];   // 32 KB
    __shared__ float red[2][128][4];                 // 4 KB

    const int tid  = threadIdx.x;
    const int lane = tid & 63;
    const int w    = tid >> 6;
    const int wm   = w >> 2, wn = w & 3;
    const int m0   = blockIdx.x * 128;

    f32x4 acc2[4][4];
#pragma unroll
    for (int i = 0; i < 4; ++i)
#pragma unroll
        for (int j = 0; j < 4; ++j) acc2[i][j] = f32x4{0.f, 0.f, 0.f, 0.f};

    auto stageB1 = [&](int c, int t) {
        const int rb  = w * 16;
        const int row = rb + (lane >> 2);
        gl_lds16(W1s + (size_t)(c * 128 + row) * 256 + t * 32 + (lane & 3) * 8,
                 &B1t[t & 1][rb * 32]);
    };
    auto stageB2 = [&](int c, int t) {
#pragma unroll
        for (int i = 0; i < 2; ++i) {
            const int rb  = i * 128 + w * 16;
            const int row = rb + (lane >> 2);
            gl_lds16(W2s + (size_t)row * 1024 + c * 128 + t * 32 + (lane & 3) * 8,
                     &B2t[t & 1][rb * 32]);
        }
    };

    // prologue: stage resident A (q1b pre-swizzled, linear copy) + B1(0,0)
#pragma unroll
    for (int i = 0; i < 8; ++i) {
        const int rb = w * 16 + i * 2;
        gl_lds16(q1b + (size_t)(m0 + rb + (lane >> 5)) * 256 + (lane & 31) * 8,
                 &As[rb * 256]);
    }
    stageB1(0, 0);
    drain_barrier();

    for (int c = 0; c < 8; ++c) {
        // ---- GEMM1: h = relu(A @ W1c + b1c), K=256, BK=32
        f32x4 acc1[4][2];
#pragma unroll
        for (int i = 0; i < 4; ++i)
#pragma unroll
            for (int j = 0; j < 2; ++j) acc1[i][j] = f32x4{0.f, 0.f, 0.f, 0.f};

        for (int t = 0; t < 8; ++t) {
            if (t < 7) stageB1(c, t + 1);
            else       stageB2(c, 0);
            const u16* b = B1t[t & 1];
            const int ko = (lane >> 4) << 3;
            short8 bfr[2];
#pragma unroll
            for (int n = 0; n < 2; ++n) {
                const int nr = wn * 32 + n * 16 + (lane & 15);
                bfr[n] = *(const short8*)&b[nr * 32 + (ko ^ ((nr & 3) << 3))];
            }
#pragma unroll
            for (int m = 0; m < 4; ++m) {
                const int ar = wm * 64 + m * 16 + (lane & 15);
                const short8 af = *(const short8*)
                    &As[ar * 256 + ((t * 32 + ko) ^ ((ar & 7) << 3))];
#pragma unroll
                for (int n = 0; n < 2; ++n)
                    acc1[m][n] = __builtin_amdgcn_mfma_f32_16x16x32_bf16(
                        af, bfr[n], acc1[m][n], 0, 0, 0);
            }
            drain_barrier();
        }

        // ---- write h (bias + relu) into Hs, swizzled
#pragma unroll
        for (int n = 0; n < 2; ++n) {
            const int col = wn * 32 + n * 16 + (lane & 15);
            const float bb = b1[c * 128 + col];
#pragma unroll
            for (int m = 0; m < 4; ++m)
#pragma unroll
                for (int r = 0; r < 4; ++r) {
                    const int row = wm * 64 + m * 16 + (lane >> 4) * 4 + r;
                    const float hv = fmaxf(acc1[m][n][r] + bb, 0.f);
                    Hs[row * 128 + (col ^ ((row & 7) << 3))] = f2bf(hv);
                }
        }
        asm volatile("s_waitcnt lgkmcnt(0)" ::: "memory");
        __builtin_amdgcn_s_barrier();

        // ---- GEMM2: acc2 += Hs @ W2c, K=128, BK=32
        for (int t = 0; t < 4; ++t) {
            if (t < 3)      stageB2(c, t + 1);
            else if (c < 7) stageB1(c + 1, 0);
            const u16* b = B2t[t & 1];
            const int ko = (lane >> 4) << 3;
            short8 bfr[4];
#pragma unroll
            for (int n = 0; n < 4; ++n) {
                const int nr = wn * 64 + n * 16 + (lane & 15);
                bfr[n] = *(const short8*)&b[nr * 32 + (ko ^ ((nr & 3) << 3))];
            }
#pragma unroll
            for (int m = 0; m < 4; ++m) {
                const int hr = wm * 64 + m * 16 + (lane & 15);
                const short8 af = *(const short8*)
                    &Hs[hr * 128 + ((t * 32 + ko) ^ ((hr & 7) << 3))];
#pragma unroll
                for (int n = 0; n < 4; ++n)
                    acc2[m][n] = __builtin_amdgcn_mfma_f32_16x16x32_bf16(
                        af, bfr[n], acc2[m][n], 0, 0, 0);
            }
            drain_barrier();
        }
    }

    // ---- epilogue: LN2(q1 (from As) + acc2 + b2) -> out f32
    float bcol[4], gcol[4], becol[4];
#pragma unroll
    for (int n = 0; n < 4; ++n) {
        const int col = wn * 64 + n * 16 + (lane & 15);
        bcol[n] = b2[col]; gcol[n] = g2[col]; becol[n] = be2[col];
    }
    float s[4][4], s2[4][4];
#pragma unroll
    for (int m = 0; m < 4; ++m)
#pragma unroll
        for (int r = 0; r < 4; ++r) {
            const int lr = wm * 64 + m * 16 + (lane >> 4) * 4 + r;
            float ps = 0.f, ps2 = 0.f;
#pragma unroll
            for (int n = 0; n < 4; ++n) {
                const int col = wn * 64 + n * 16 + (lane & 15);
                const float q = bf2f(As[lr * 256 + (col ^ ((lr & 7) << 3))]);
                const float v = acc2[m][n][r] + bcol[n] + q;
                acc2[m][n][r] = v;
                ps += v; ps2 += v * v;
            }
#pragma unroll
            for (int o = 1; o < 16; o <<= 1) {
                ps  += __shfl_xor(ps,  o);
                ps2 += __shfl_xor(ps2, o);
            }
            s[m][r] = ps; s2[m][r] = ps2;
        }
    if ((lane & 15) == 0) {
#pragma unroll
        for (int m = 0; m < 4; ++m)
#pragma unroll
            for (int r = 0; r < 4; ++r) {
                const int lr = wm * 64 + m * 16 + (lane >> 4) * 4 + r;
                red[0][lr][wn] = s[m][r];
                red[1][lr][wn] = s2[m][r];
            }
    }
    __syncthreads();
    if (tid < 128) {
        const float ss  = red[0][tid][0] + red[0][tid][1] + red[0][tid][2] + red[0][tid][3];
        const float ss2 = red[1][tid][0] + red[1][tid][1] + red[1][tid][2] + red[1][tid][3];
        const float mean = ss * (1.f / 256.f);
        const float var  = fmaxf(ss2 * (1.f / 256.f) - mean * mean, 0.f);
        red[0][tid][0] = mean;
        red[1][tid][0] = rsqrtf(var + 1e-5f);
    }
    __syncthreads();
#pragma unroll
    for (int m = 0; m < 4; ++m)
#pragma unroll
        for (int r = 0; r < 4; ++r) {
            const int lr = wm * 64 + m * 16 + (lane >> 4) * 4 + r;
            const float mean = red[0][lr][0];
            const float rstd = red[1][lr][0];
#pragma unroll
            for (int n = 0; n < 4; ++n) {
                const int col = wn * 64 + n * 16 + (lane & 15);
                out[(size_t)(m0 + lr) * 256 + col] =
                    (acc2[m][n][r] - mean) * rstd * gcol[n] + becol[n];
            }
        }
}

// ---------------------------------------------------------------------------
// 4-wave 128x128 MFMA GEMM (R4 structure) — used only for the oaw projection.
// ---------------------------------------------------------------------------
__global__ __launch_bounds__(256) void gemm_oaw(
    const float* __restrict__ Av, const u16* __restrict__ Bt,
    const float* __restrict__ bias, float* __restrict__ C,
    int M, int K, int Nreal, int ldc)
{
    __shared__ __align__(16) u16 Asl[2][128 * 32];
    __shared__ __align__(16) u16 Bsl[2][128 * 32];

    const int tid  = threadIdx.x;
    const int lane = tid & 63;
    const int w    = tid >> 6;
    const int wr   = (w >> 1) * 64;
    const int wc   = (w & 1) * 64;
    const int m0   = blockIdx.y * 128;
    const int n0   = blockIdx.x * 128;

    const int srow = lane >> 2;
    const int scol = (lane & 3) << 3;
    const u16* bG = Bt + (size_t)(n0 + w * 32 + srow) * K + scol;
    const size_t rstep16 = (size_t)16 * K;

    const int ar  = lane >> 3;
    const int ac  = (lane & 7) << 2;
    const float* aGf = Av + (size_t)(m0 + w * 32 + ar) * K + ac;

    const int aRoff = (wr + (lane & 15)) * 32 + (lane >> 4) * 8;
    const int bRoff = (wc + (lane & 15)) * 32 + (lane >> 4) * 8;

    f32x4 acc[4][4];
#pragma unroll
    for (int i = 0; i < 4; ++i)
#pragma unroll
        for (int j = 0; j < 4; ++j) acc[i][j] = f32x4{0.f, 0.f, 0.f, 0.f};

    float4 a4[4];
    const int nt = K >> 5;

#pragma unroll
    for (int rep = 0; rep < 4; ++rep)
        a4[rep] = *(const float4*)(aGf + (size_t)(rep * 8) * K);
#pragma unroll
    for (int rep = 0; rep < 4; ++rep) {
        ushort4 v{f2bf(a4[rep].x), f2bf(a4[rep].y), f2bf(a4[rep].z), f2bf(a4[rep].w)};
        *(ushort4*)&Asl[0][(w * 32 + rep * 8 + ar) * 32 + ac] = v;
    }
    gl_lds16(bG, &Bsl[0][(w * 32) * 32]);
    gl_lds16(bG + rstep16, &Bsl[0][(w * 32 + 16) * 32]);
    drain_barrier();

    for (int t = 0; t < nt; ++t) {
        const int cur = t & 1, nxt = cur ^ 1;
        const int k0n = (t + 1) << 5;
        const bool has_next = (t + 1 < nt);
        if (has_next) {
#pragma unroll
            for (int rep = 0; rep < 4; ++rep)
                a4[rep] = *(const float4*)(aGf + k0n + (size_t)(rep * 8) * K);
            gl_lds16(bG + k0n, &Bsl[nxt][(w * 32) * 32]);
            gl_lds16(bG + k0n + rstep16, &Bsl[nxt][(w * 32 + 16) * 32]);
        }
        short8 af[4], bfr[4];
#pragma unroll
        for (int m = 0; m < 4; ++m) af[m]  = *(const short8*)&Asl[cur][aRoff + m * 16 * 32];
#pragma unroll
        for (int n = 0; n < 4; ++n) bfr[n] = *(const short8*)&Bsl[cur][bRoff + n * 16 * 32];
#pragma unroll
        for (int m = 0; m < 4; ++m)
#pragma unroll
            for (int n = 0; n < 4; ++n)
                acc[m][n] = __builtin_amdgcn_mfma_f32_16x16x32_bf16(
                    af[m], bfr[n], acc[m][n], 0, 0, 0);
        if (has_next) {
#pragma unroll
            for (int rep = 0; rep < 4; ++rep) {
                ushort4 v{f2bf(a4[rep].x), f2bf(a4[rep].y), f2bf(a4[rep].z), f2bf(a4[rep].w)};
                *(ushort4*)&Asl[nxt][(w * 32 + rep * 8 + ar) * 32 + ac] = v;
            }
        }
        drain_barrier();
    }

#pragma unroll
    for (int n = 0; n < 4; ++n) {
        const int gc = n0 + wc + n * 16 + (lane & 15);
        if (gc >= Nreal) continue;
        const float bv = bias[gc];
        const int gr0 = m0 + wr + (lane >> 4) * 4;
#pragma unroll
        for (int m = 0; m < 4; ++m)
#pragma unroll
            for (int r = 0; r < 4; ++r)
                C[(size_t)(gr0 + m * 16 + r) * ldc + gc] = acc[m][n][r] + bv;
    }
}

// ---------------------------------------------------------------------------
// Weight prep: B^T bf16, pre-swizzled. storage[n][kd] = W[(kd^swz)][n],
// swz = (n&7)<<3 for Wv/Wo (BK=64 slices), (n&3)<<3 for W1/W2 (BK=32 slices).
// Woa: linear [128][256] (old-format for gemm_oaw) + padded bias.
// ---------------------------------------------------------------------------
__global__ __launch_bounds__(256) void prep_all(
    const float* __restrict__ Wv, const float* __restrict__ Wo,
    const float* __restrict__ W1, const float* __restrict__ W2,
    const float* __restrict__ Woff, const float* __restrict__ Waw,
    const float* __restrict__ boff, const float* __restrict__ baw,
    u16* __restrict__ Wvs, u16* __restrict__ Wos,
    u16* __restrict__ W1s, u16* __restrict__ W2s,
    u16* __restrict__ Woa, float* __restrict__ boa)
{
    const int idx = blockIdx.x * 256 + threadIdx.x;
    if (idx < 65536) {
        const int n = idx >> 8, kd = idx & 255;
        Wvs[idx] = f2bf(Wv[(size_t)(kd ^ ((n & 7) << 3)) * 256 + n]);
    } else if (idx < 131072) {
        const int i = idx - 65536, n = i >> 8, kd = i & 255;
        Wos[i] = f2bf(Wo[(size_t)(kd ^ ((n & 7) << 3)) * 256 + n]);
    } else if (idx < 393216) {
        const int i = idx - 131072, n = i >> 8, kd = i & 255;   // n: 0..1023
        W1s[i] = f2bf(W1[(size_t)(kd ^ ((n & 3) << 3)) * 1024 + n]);
    } else if (idx < 655360) {
        const int i = idx - 393216, n = i >> 10, kd = i & 1023;
        W2s[i] = f2bf(W2[(size_t)(kd ^ ((n & 3) << 3)) * 256 + n]);
    } else if (idx < 688128) {
        const int i = idx - 655360, n = i >> 8, k = i & 255;
        float v = 0.f;
        if (n < 64)      v = Woff[(size_t)k * 64 + n];
        else if (n < 96) v = Waw[(size_t)k * 32 + (n - 64)];
        Woa[i] = f2bf(v);
    } else if (idx < 688256) {
        const int i = idx - 688128;
        boa[i] = (i < 64) ? boff[i] : (i < 96 ? baw[i - 64] : 0.f);
    }
}

// ---------------------------------------------------------------------------
// Bilinear sampling + attention-weight combine (R3/R4 layout).
// ---------------------------------------------------------------------------
__global__ __launch_bounds__(256) void sample_attn(
    const u16* __restrict__ val, const float* __restrict__ oaw,
    const float* __restrict__ refp, u16* __restrict__ attn)
{
    const int t   = threadIdx.x;
    const int gid = blockIdx.x * 64 + (t >> 2);
    const int c0  = (t & 3) << 3;
    const int h   = gid & (NH_ - 1);
    const int bq  = gid >> 3;

    const float* row = oaw + (size_t)bq * 96;
    const float rx = refp[(size_t)bq * 2 + 0] * (float)WIMG;
    const float ry = refp[(size_t)bq * 2 + 1] * (float)HIMG;

    const float4 aw4 = *(const float4*)(row + 64 + h * 4);
    const float mx = fmaxf(fmaxf(aw4.x, aw4.y), fmaxf(aw4.z, aw4.w));
    const float e0 = __expf(aw4.x - mx), e1 = __expf(aw4.y - mx);
    const float e2 = __expf(aw4.z - mx), e3 = __expf(aw4.w - mx);
    const float inv = 1.f / (e0 + e1 + e2 + e3);
    const float w4[4] = {e0 * inv, e1 * inv, e2 * inv, e3 * inv};

    const int b = bq / Lq_;
    const u16* vb = val + (size_t)b * LIN * C_ + h * 32 + c0;

    float acc[8] = {};
#pragma unroll
    for (int p = 0; p < NP_; ++p) {
        const float2 off = *(const float2*)(row + (h * 4 + p) * 2);
        const float x = rx + off.x - 0.5f;
        const float y = ry + off.y - 0.5f;
        const float xf = floorf(x), yf = floorf(y);
        const float lx = x - xf, ly = y - yf;
        const int x0 = (int)xf, y0 = (int)yf;
        const float wp = w4[p];
        const float w00 = wp * (1.f - lx) * (1.f - ly);
        const float w10 = wp * lx * (1.f - ly);
        const float w01 = wp * (1.f - lx) * ly;
        const float w11 = wp * lx * ly;

#pragma unroll
        for (int c = 0; c < 4; ++c) {
            const int xi = x0 + (c & 1);
            const int yi = y0 + (c >> 1);
            const float wc = (c == 0) ? w00 : (c == 1) ? w10 : (c == 2) ? w01 : w11;
            const bool v = ((unsigned)xi < (unsigned)WIMG) & ((unsigned)yi < (unsigned)HIMG);
            const int idx = v ? (yi * WIMG + xi) : 0;
            const float w = v ? wc : 0.f;
            const short8 d = *(const short8*)(vb + (size_t)idx * C_);
#pragma unroll
            for (int j = 0; j < 8; ++j)
                acc[j] = fmaf(w, bf2f(((const u16*)&d)[j]), acc[j]);
        }
    }

    union { short8 s; u16 u[8]; } o;
#pragma unroll
    for (int j = 0; j < 8; ++j) o.u[j] = f2bf(acc[j]);
    *(short8*)(attn + (size_t)bq * C_ + h * 32 + c0) = o.s;
}

// ---------------------------------------------------------------------------
extern "C" void kernel_launch(void* const* d_in, const int* in_sizes, int n_in,
                              void* d_out, int out_size, void* d_ws, size_t ws_size,
                              hipStream_t stream)
{
    const float* query = (const float*)d_in[0];
    const float* src   = (const float*)d_in[1];
    const float* refp  = (const float*)d_in[2];
    const float* W_off = (const float*)d_in[5];
    const float* b_off = (const float*)d_in[6];
    const float* W_aw  = (const float*)d_in[7];
    const float* b_aw  = (const float*)d_in[8];
    const float* W_val = (const float*)d_in[9];
    const float* b_val = (const float*)d_in[10];
    const float* W_out = (const float*)d_in[11];
    const float* b_out = (const float*)d_in[12];
    const float* g1    = (const float*)d_in[13];
    const float* be1   = (const float*)d_in[14];
    const float* W1    = (const float*)d_in[15];
    const float* b1    = (const float*)d_in[16];
    const float* W2    = (const float*)d_in[17];
    const float* b2    = (const float*)d_in[18];
    const float* g2    = (const float*)d_in[19];
    const float* be2   = (const float*)d_in[20];
    float* out = (float*)d_out;

    char* ws = (char*)d_ws;
    const int R = B_ * Lq_;  // 80000

    // Workspace (no aliasing needed; ~155 MB of ~327 MB):
    u16*  val  = (u16*)(ws + 0);           // 40.96 MB
    float* oaw = (float*)(ws + 40960000);  // 30.72 MB
    u16*  attn = (u16*)(ws + 71680000);    // 40.96 MB
    u16*  q1b  = (u16*)(ws + 112640000);   // 40.96 MB (swizzled layout)
    u16*  Wvs  = (u16*)(ws + 153600000);
    u16*  Wos  = (u16*)(ws + 153600000 + 131072);
    u16*  W1s  = (u16*)(ws + 153600000 + 262144);
    u16*  W2s  = (u16*)(ws + 153600000 + 786432);
    u16*  Woa  = (u16*)(ws + 153600000 + 1310720);
    float* boa = (float*)(ws + 153600000 + 1376256);

    prep_all<<<2689, 256, 0, stream>>>(W_val, W_out, W1, W2, W_off, W_aw,
                                       b_off, b_aw, Wvs, Wos, W1s, W2s,
                                       Woa, boa);

    // value = src @ W_val + b_val  (f32 A converted in-kernel) -> bf16 linear
    gemm256<true, false><<<625, 512, 0, stream>>>(
        src, Wvs, b_val, nullptr, nullptr, nullptr, val, 256);

    // oaw = query @ [W_off|W_aw] + bias  (N padded 96->128)
    gemm_oaw<<<dim3(1, 625), 256, 0, stream>>>(
        query, Woa, boa, oaw, R, 256, 96, 96);

    // bilinear sampling + softmax combine -> attn bf16 linear
    sample_attn<<<10000, 256, 0, stream>>>(val, oaw, refp, attn);

    // q1 = LN(query + attn @ W_out + b_out) -> q1b bf16 (swizzled layout)
    gemm256<false, true><<<625, 512, 0, stream>>>(
        attn, Wos, b_out, query, g1, be1, q1b, 256);

    // out = LN(q1 + FFN(q1)) -> f32, h stays in LDS
    ffn_fused<<<625, 512, 0, stream>>>(q1b, W1s, W2s, b1, b2, g2, be2, out);
}

// Round 6
// 310.919 us; speedup vs baseline: 7.3902x; 1.0532x over previous
//
#include <hip/hip_runtime.h>
#include <hip/hip_bf16.h>

typedef __hip_bfloat16 bf16;
typedef unsigned short u16;
typedef short short8 __attribute__((ext_vector_type(8)));
typedef float f32x4 __attribute__((ext_vector_type(4)));

static constexpr int B_   = 8;
static constexpr int Lq_  = 10000;
static constexpr int C_   = 256;
static constexpr int NH_  = 8;
static constexpr int NP_  = 4;
static constexpr int HIMG = 100;
static constexpr int WIMG = 100;
static constexpr int LIN  = 10000;   // H*W

__device__ __forceinline__ u16 f2bf(float x) {
    union { bf16 b; u16 u; } cv; cv.b = __float2bfloat16(x); return cv.u;
}
__device__ __forceinline__ float bf2f(u16 u) {
    return __uint_as_float((unsigned)u << 16);
}

// Async global -> LDS, 16 B per lane. LDS dest wave-uniform; HW writes
// base + lane*16 (guide §5 m104).
__device__ __forceinline__ void gl_lds16(const void* g, void* l) {
    __builtin_amdgcn_global_load_lds(
        (const __attribute__((address_space(1))) void*)g,
        (__attribute__((address_space(3))) void*)l, 16, 0, 0);
}
__device__ __forceinline__ void drain_barrier() {
    asm volatile("s_waitcnt vmcnt(0) lgkmcnt(0)" ::: "memory");
    __builtin_amdgcn_s_barrier();
}
#define VMW(N) asm volatile("s_waitcnt vmcnt(" #N ")" ::: "memory")
#define LKW0() asm volatile("s_waitcnt lgkmcnt(0)" ::: "memory")
#define BAR()  __builtin_amdgcn_s_barrier()

// Swizzle convention (rule #21, both-sides-or-neither):
//   storage[row][e] = logical[row][e ^ ((row&S)<<3)]   (granule = 8 elem = 16B)
//   S=7 for >=128B rows, S=3 for 64B rows. Stagers copy storage linearly;
//   readers XOR the same pattern.

// ---------------------------------------------------------------------------
// gemm256: C[M][256] = A[M][K] @ B + bias, tile 128x256, 8 waves (2m x 4n),
// BK=64, 2-phase dbuf staging. B pre-swizzled [256][K] (S=7 per 64-elem slice).
// AF32: A is f32, reg-staged+converted; else bf16, gl_lds w/ source swizzle.
// LN: epilogue += resid (f32), row-LayerNorm(g,be), write u16 SWIZZLED (S=7).
// else: plain bias epilogue, write u16 linear.
// ---------------------------------------------------------------------------
template <bool AF32, bool LN>
__global__ __launch_bounds__(512, 2) void gemm256(
    const void* __restrict__ Av, const u16* __restrict__ Bg,
    const float* __restrict__ bias, const float* __restrict__ resid,
    const float* __restrict__ gw, const float* __restrict__ bw,
    u16* __restrict__ Co, int K)
{
    __shared__ __align__(16) u16 At[2][128 * 64];
    __shared__ __align__(16) u16 Bt[2][256 * 64];
    __shared__ float red[2][128][4];

    const int tid  = threadIdx.x;
    const int lane = tid & 63;
    const int w    = tid >> 6;
    const int wm   = w >> 2, wn = w & 3;
    const int m0   = blockIdx.x * 128;

    f32x4 acc[4][4];
#pragma unroll
    for (int i = 0; i < 4; ++i)
#pragma unroll
        for (int j = 0; j < 4; ++j) acc[i][j] = f32x4{0.f, 0.f, 0.f, 0.f};

    auto stageA = [&](int t) {
        const int kt = t << 6;
        if constexpr (AF32) {
            const int row = tid >> 2;
            const int k0  = (tid & 3) << 4;
            const float* s = (const float*)Av + (size_t)(m0 + row) * K + kt + k0;
            float4 v0 = *(const float4*)(s + 0);
            float4 v1 = *(const float4*)(s + 4);
            float4 v2 = *(const float4*)(s + 8);
            float4 v3 = *(const float4*)(s + 12);
            union { short8 s8; u16 u[8]; } ga, gb;
            ga.u[0]=f2bf(v0.x); ga.u[1]=f2bf(v0.y); ga.u[2]=f2bf(v0.z); ga.u[3]=f2bf(v0.w);
            ga.u[4]=f2bf(v1.x); ga.u[5]=f2bf(v1.y); ga.u[6]=f2bf(v1.z); ga.u[7]=f2bf(v1.w);
            gb.u[0]=f2bf(v2.x); gb.u[1]=f2bf(v2.y); gb.u[2]=f2bf(v2.z); gb.u[3]=f2bf(v2.w);
            gb.u[4]=f2bf(v3.x); gb.u[5]=f2bf(v3.y); gb.u[6]=f2bf(v3.z); gb.u[7]=f2bf(v3.w);
            u16* d = &At[t & 1][row * 64];
            *(short8*)&d[(k0)     ^ ((row & 7) << 3)] = ga.s8;
            *(short8*)&d[(k0 + 8) ^ ((row & 7) << 3)] = gb.s8;
        } else {
#pragma unroll
            for (int i = 0; i < 2; ++i) {
                const int rb  = w * 16 + i * 8;
                const int row = rb + (lane >> 3);
                const int gs  = (lane & 7) ^ (row & 7);
                gl_lds16((const u16*)Av + (size_t)(m0 + row) * K + kt + gs * 8,
                         &At[t & 1][rb * 64]);
            }
        }
    };
    auto stageB = [&](int t) {
        const int kt = t << 6;
#pragma unroll
        for (int i = 0; i < 4; ++i) {
            const int rb  = w * 32 + i * 8;
            const int row = rb + (lane >> 3);
            gl_lds16(Bg + (size_t)row * K + kt + (lane & 7) * 8,
                     &Bt[t & 1][rb * 64]);
        }
    };
    auto compute = [&](int t) {
        const u16* a = At[t & 1];
        const u16* b = Bt[t & 1];
#pragma unroll
        for (int ks = 0; ks < 2; ++ks) {
            const int ko = ks * 32 + ((lane >> 4) << 3);
            short8 bfr[4];
#pragma unroll
            for (int n = 0; n < 4; ++n) {
                const int nr = wn * 64 + n * 16 + (lane & 15);
                bfr[n] = *(const short8*)&b[nr * 64 + (ko ^ ((nr & 7) << 3))];
            }
#pragma unroll
            for (int m = 0; m < 4; ++m) {
                const int ar = wm * 64 + m * 16 + (lane & 15);
                const short8 af = *(const short8*)&a[ar * 64 + (ko ^ ((ar & 7) << 3))];
#pragma unroll
                for (int n = 0; n < 4; ++n)
                    acc[m][n] = __builtin_amdgcn_mfma_f32_16x16x32_bf16(
                        af, bfr[n], acc[m][n], 0, 0, 0);
            }
        }
    };

    stageA(0); stageB(0);
    drain_barrier();
    const int nt = K >> 6;
    for (int t = 0; t < nt; ++t) {
        if (t + 1 < nt) { stageA(t + 1); stageB(t + 1); }
        compute(t);
        drain_barrier();
    }

    // epilogue. C/D frag: col = lane&15 (+n*16+wn*64), row = (lane>>4)*4+r (+m*16+wm*64)
    float bcol[4], gcol[4], becol[4];
#pragma unroll
    for (int n = 0; n < 4; ++n) {
        const int col = wn * 64 + n * 16 + (lane & 15);
        bcol[n] = bias[col];
        if (LN) { gcol[n] = gw[col]; becol[n] = bw[col]; }
    }

    if constexpr (!LN) {
#pragma unroll
        for (int m = 0; m < 4; ++m)
#pragma unroll
            for (int r = 0; r < 4; ++r) {
                const int lr = wm * 64 + m * 16 + (lane >> 4) * 4 + r;
#pragma unroll
                for (int n = 0; n < 4; ++n) {
                    const int col = wn * 64 + n * 16 + (lane & 15);
                    Co[(size_t)(m0 + lr) * 256 + col] = f2bf(acc[m][n][r] + bcol[n]);
                }
            }
    } else {
        float s[4][4], s2[4][4];
#pragma unroll
        for (int m = 0; m < 4; ++m)
#pragma unroll
            for (int r = 0; r < 4; ++r) {
                const int lr = wm * 64 + m * 16 + (lane >> 4) * 4 + r;
                float ps = 0.f, ps2 = 0.f;
#pragma unroll
                for (int n = 0; n < 4; ++n) {
                    const int col = wn * 64 + n * 16 + (lane & 15);
                    float v = acc[m][n][r] + bcol[n]
                            + resid[(size_t)(m0 + lr) * 256 + col];
                    acc[m][n][r] = v;
                    ps += v; ps2 += v * v;
                }
#pragma unroll
                for (int o = 1; o < 16; o <<= 1) {
                    ps  += __shfl_xor(ps,  o);
                    ps2 += __shfl_xor(ps2, o);
                }
                s[m][r] = ps; s2[m][r] = ps2;
            }
        if ((lane & 15) == 0) {
#pragma unroll
            for (int m = 0; m < 4; ++m)
#pragma unroll
                for (int r = 0; r < 4; ++r) {
                    const int lr = wm * 64 + m * 16 + (lane >> 4) * 4 + r;
                    red[0][lr][wn] = s[m][r];
                    red[1][lr][wn] = s2[m][r];
                }
        }
        __syncthreads();
        if (tid < 128) {
            const float ss  = red[0][tid][0] + red[0][tid][1] + red[0][tid][2] + red[0][tid][3];
            const float ss2 = red[1][tid][0] + red[1][tid][1] + red[1][tid][2] + red[1][tid][3];
            const float mean = ss * (1.f / 256.f);
            const float var  = fmaxf(ss2 * (1.f / 256.f) - mean * mean, 0.f);
            red[0][tid][0] = mean;
            red[1][tid][0] = rsqrtf(var + 1e-5f);
        }
        __syncthreads();
#pragma unroll
        for (int m = 0; m < 4; ++m)
#pragma unroll
            for (int r = 0; r < 4; ++r) {
                const int lr = wm * 64 + m * 16 + (lane >> 4) * 4 + r;
                const float mean = red[0][lr][0];
                const float rstd = red[1][lr][0];
#pragma unroll
                for (int n = 0; n < 4; ++n) {
                    const int col = wn * 64 + n * 16 + (lane & 15);
                    const float o = (acc[m][n][r] - mean) * rstd * gcol[n] + becol[n];
                    Co[(size_t)(m0 + lr) * 256 + (col ^ ((lr & 7) << 3))] = f2bf(o);
                }
            }
    }
}

// ---------------------------------------------------------------------------
// ffn_fused v2 — counted-vmcnt schedule (T4), no drains in main loop.
// Per 128-row block: As resident (swizzled q1b). 8 chunks of DFF=128:
//   GEMM1 (8 steps, BK=32): B1 ring-3, issue 2 ahead, vmcnt(1)/step.
//   Hs (padded ld=136) <- relu(acc1+b1).
//   GEMM2 (4 steps, BK=32): B2 ring-2; B2_0/1 prefetched during G1 t6/t7;
//   next-chunk B1_0..2 prefetched during G2 u0..u2.
// One s_barrier per step; waits are counted so loads span barriers.
// ---------------------------------------------------------------------------
__global__ __launch_bounds__(512) void ffn_fused(
    const u16* __restrict__ q1b, const u16* __restrict__ W1s,
    const u16* __restrict__ W2s, const float* __restrict__ b1,
    const float* __restrict__ b2, const float* __restrict__ g2,
    const float* __restrict__ be2, float* __restrict__ out)
{
    __shared__ __align__(16) u16 As[128 * 256];      // 64 KB, resident
    __shared__ __align__(16) u16 Hs[128 * 136];      // 34 KB, padded (no swz)
    __shared__ __align__(16) u16 B1t[3][128 * 32];   // 24 KB ring
    __shared__ __align__(16) u16 B2t[2][256 * 32];   // 32 KB ring
    // red aliases Hs (only used in epilogue, after last Hs read)
    float (*red)[128][4] = (float (*)[128][4])Hs;

    const int tid  = threadIdx.x;
    const int lane = tid & 63;
    const int w    = tid >> 6;
    const int wm   = w >> 2, wn = w & 3;
    const int m0   = blockIdx.x * 128;

    f32x4 acc2[4][4];
#pragma unroll
    for (int i = 0; i < 4; ++i)
#pragma unroll
        for (int j = 0; j < 4; ++j) acc2[i][j] = f32x4{0.f, 0.f, 0.f, 0.f};

    // per wave: 1 load
    auto issueB1 = [&](int c, int t, int buf) {
        const int rb  = w * 16;
        const int row = rb + (lane >> 2);
        gl_lds16(W1s + (size_t)(c * 128 + row) * 256 + t * 32 + (lane & 3) * 8,
                 &B1t[buf][rb * 32]);
    };
    // per wave: 2 loads
    auto issueB2 = [&](int c, int u, int buf) {
#pragma unroll
        for (int i = 0; i < 2; ++i) {
            const int rb  = i * 128 + w * 16;
            const int row = rb + (lane >> 2);
            gl_lds16(W2s + (size_t)row * 1024 + c * 128 + u * 32 + (lane & 3) * 8,
                     &B2t[buf][rb * 32]);
        }
    };

    // ---- prologue: As (8 loads/wave) + B1 bufs 0..2 for chunk 0
#pragma unroll
    for (int i = 0; i < 8; ++i) {
        const int rb = w * 16 + i * 2;
        gl_lds16(q1b + (size_t)(m0 + rb + (lane >> 5)) * 256 + (lane & 31) * 8,
                 &As[rb * 256]);
    }
    issueB1(0, 0, 0); issueB1(0, 1, 1); issueB1(0, 2, 2);
    VMW(2); BAR();   // B1_0 + As done (B1_1, B1_2 may be in flight)

    for (int c = 0; c < 8; ++c) {
        f32x4 acc1[4][2];
#pragma unroll
        for (int i = 0; i < 4; ++i)
#pragma unroll
            for (int j = 0; j < 2; ++j) acc1[i][j] = f32x4{0.f, 0.f, 0.f, 0.f};

        auto g1 = [&](int t, int buf) {
            const u16* bb = B1t[buf];
            const int ko = (lane >> 4) << 3;
            short8 bfr[2];
#pragma unroll
            for (int n = 0; n < 2; ++n) {
                const int nr = wn * 32 + n * 16 + (lane & 15);
                bfr[n] = *(const short8*)&bb[nr * 32 + (ko ^ ((nr & 3) << 3))];
            }
#pragma unroll
            for (int m = 0; m < 4; ++m) {
                const int ar = wm * 64 + m * 16 + (lane & 15);
                const short8 af = *(const short8*)
                    &As[ar * 256 + ((t * 32 + ko) ^ ((ar & 7) << 3))];
#pragma unroll
                for (int n = 0; n < 2; ++n)
                    acc1[m][n] = __builtin_amdgcn_mfma_f32_16x16x32_bf16(
                        af, bfr[n], acc1[m][n], 0, 0, 0);
            }
        };
        auto g2s = [&](int u, int buf) {
            const u16* bb = B2t[buf];
            const int ko = (lane >> 4) << 3;
            short8 bfr[4];
#pragma unroll
            for (int n = 0; n < 4; ++n) {
                const int nr = wn * 64 + n * 16 + (lane & 15);
                bfr[n] = *(const short8*)&bb[nr * 32 + (ko ^ ((nr & 3) << 3))];
            }
#pragma unroll
            for (int m = 0; m < 4; ++m) {
                const int hr = wm * 64 + m * 16 + (lane & 15);
                const short8 af = *(const short8*)&Hs[hr * 136 + u * 32 + ko];
#pragma unroll
                for (int n = 0; n < 4; ++n)
                    acc2[m][n] = __builtin_amdgcn_mfma_f32_16x16x32_bf16(
                        af, bfr[n], acc2[m][n], 0, 0, 0);
            }
        };

        // ---- GEMM1, 8 steps, one barrier each, counted waits
        g1(0, 0);
        if (c == 0) { VMW(1); } else { VMW(3); }   // B1_1 ready
        BAR();
        issueB1(c, 3, 0); g1(1, 1); VMW(1); BAR();  // B1_2 ready
        issueB1(c, 4, 1); g1(2, 2); VMW(1); BAR();
        issueB1(c, 5, 2); g1(3, 0); VMW(1); BAR();
        issueB1(c, 6, 0); g1(4, 1); VMW(1); BAR();
        issueB1(c, 7, 1); g1(5, 2); VMW(1); BAR();
        issueB2(c, 0, 0); g1(6, 0); VMW(2); BAR();  // B1_7 ready
        issueB2(c, 1, 1); g1(7, 1); VMW(2); BAR();  // B2_0 ready

        // ---- h -> Hs (bias+relu), padded rows (bank-rotating, no swizzle)
#pragma unroll
        for (int n = 0; n < 2; ++n) {
            const int col = wn * 32 + n * 16 + (lane & 15);
            const float bb = b1[c * 128 + col];
#pragma unroll
            for (int m = 0; m < 4; ++m)
#pragma unroll
                for (int r = 0; r < 4; ++r) {
                    const int row = wm * 64 + m * 16 + (lane >> 4) * 4 + r;
                    Hs[row * 136 + col] = f2bf(fmaxf(acc1[m][n][r] + bb, 0.f));
                }
        }
        LKW0(); BAR();

        // ---- GEMM2, 4 steps; prefetch next-chunk B1 (c=7 reads into W2s
        // region -> valid memory, data unused)
        issueB1(c + 1, 0, 0);                    g2s(0, 0); VMW(1); BAR(); // B2_1 ready
        issueB2(c, 2, 0); issueB1(c + 1, 1, 1);  g2s(1, 1); VMW(1); BAR(); // B2_2 ready
        issueB2(c, 3, 1); issueB1(c + 1, 2, 2);  g2s(2, 0); VMW(1); BAR(); // B2_3 ready
        g2s(3, 1); VMW(6); BAR();                // next-chunk B1_0 ready
    }
    asm volatile("s_waitcnt vmcnt(0)" ::: "memory");
    BAR();

    // ---- epilogue: LN2(q1 (from As) + acc2 + b2) -> out f32
    float bcol[4], gcol[4], becol[4];
#pragma unroll
    for (int n = 0; n < 4; ++n) {
        const int col = wn * 64 + n * 16 + (lane & 15);
        bcol[n] = b2[col]; gcol[n] = g2[col]; becol[n] = be2[col];
    }
    float s[4][4], s2[4][4];
#pragma unroll
    for (int m = 0; m < 4; ++m)
#pragma unroll
        for (int r = 0; r < 4; ++r) {
            const int lr = wm * 64 + m * 16 + (lane >> 4) * 4 + r;
            float ps = 0.f, ps2 = 0.f;
#pragma unroll
            for (int n = 0; n < 4; ++n) {
                const int col = wn * 64 + n * 16 + (lane & 15);
                const float q = bf2f(As[lr * 256 + (col ^ ((lr & 7) << 3))]);
                const float v = acc2[m][n][r] + bcol[n] + q;
                acc2[m][n][r] = v;
                ps += v; ps2 += v * v;
            }
#pragma unroll
            for (int o = 1; o < 16; o <<= 1) {
                ps  += __shfl_xor(ps,  o);
                ps2 += __shfl_xor(ps2, o);
            }
            s[m][r] = ps; s2[m][r] = ps2;
        }
    if ((lane & 15) == 0) {
#pragma unroll
        for (int m = 0; m < 4; ++m)
#pragma unroll
            for (int r = 0; r < 4; ++r) {
                const int lr = wm * 64 + m * 16 + (lane >> 4) * 4 + r;
                red[0][lr][wn] = s[m][r];
                red[1][lr][wn] = s2[m][r];
            }
    }
    __syncthreads();
    if (tid < 128) {
        const float ss  = red[0][tid][0] + red[0][tid][1] + red[0][tid][2] + red[0][tid][3];
        const float ss2 = red[1][tid][0] + red[1][tid][1] + red[1][tid][2] + red[1][tid][3];
        const float mean = ss * (1.f / 256.f);
        const float var  = fmaxf(ss2 * (1.f / 256.f) - mean * mean, 0.f);
        red[0][tid][0] = mean;
        red[1][tid][0] = rsqrtf(var + 1e-5f);
    }
    __syncthreads();
#pragma unroll
    for (int m = 0; m < 4; ++m)
#pragma unroll
        for (int r = 0; r < 4; ++r) {
            const int lr = wm * 64 + m * 16 + (lane >> 4) * 4 + r;
            const float mean = red[0][lr][0];
            const float rstd = red[1][lr][0];
#pragma unroll
            for (int n = 0; n < 4; ++n) {
                const int col = wn * 64 + n * 16 + (lane & 15);
                out[(size_t)(m0 + lr) * 256 + col] =
                    (acc2[m][n][r] - mean) * rstd * gcol[n] + becol[n];
            }
        }
}

// ---------------------------------------------------------------------------
// 4-wave 128x128 MFMA GEMM (R4 structure) — used only for the oaw projection.
// ---------------------------------------------------------------------------
__global__ __launch_bounds__(256) void gemm_oaw(
    const float* __restrict__ Av, const u16* __restrict__ Bt,
    const float* __restrict__ bias, float* __restrict__ C,
    int M, int K, int Nreal, int ldc)
{
    __shared__ __align__(16) u16 Asl[2][128 * 32];
    __shared__ __align__(16) u16 Bsl[2][128 * 32];

    const int tid  = threadIdx.x;
    const int lane = tid & 63;
    const int w    = tid >> 6;
    const int wr   = (w >> 1) * 64;
    const int wc   = (w & 1) * 64;
    const int m0   = blockIdx.y * 128;
    const int n0   = blockIdx.x * 128;

    const int srow = lane >> 2;
    const int scol = (lane & 3) << 3;
    const u16* bG = Bt + (size_t)(n0 + w * 32 + srow) * K + scol;
    const size_t rstep16 = (size_t)16 * K;

    const int ar  = lane >> 3;
    const int ac  = (lane & 7) << 2;
    const float* aGf = Av + (size_t)(m0 + w * 32 + ar) * K + ac;

    const int aRoff = (wr + (lane & 15)) * 32 + (lane >> 4) * 8;
    const int bRoff = (wc + (lane & 15)) * 32 + (lane >> 4) * 8;

    f32x4 acc[4][4];
#pragma unroll
    for (int i = 0; i < 4; ++i)
#pragma unroll
        for (int j = 0; j < 4; ++j) acc[i][j] = f32x4{0.f, 0.f, 0.f, 0.f};

    float4 a4[4];
    const int nt = K >> 5;

#pragma unroll
    for (int rep = 0; rep < 4; ++rep)
        a4[rep] = *(const float4*)(aGf + (size_t)(rep * 8) * K);
#pragma unroll
    for (int rep = 0; rep < 4; ++rep) {
        ushort4 v{f2bf(a4[rep].x), f2bf(a4[rep].y), f2bf(a4[rep].z), f2bf(a4[rep].w)};
        *(ushort4*)&Asl[0][(w * 32 + rep * 8 + ar) * 32 + ac] = v;
    }
    gl_lds16(bG, &Bsl[0][(w * 32) * 32]);
    gl_lds16(bG + rstep16, &Bsl[0][(w * 32 + 16) * 32]);
    drain_barrier();

    for (int t = 0; t < nt; ++t) {
        const int cur = t & 1, nxt = cur ^ 1;
        const int k0n = (t + 1) << 5;
        const bool has_next = (t + 1 < nt);
        if (has_next) {
#pragma unroll
            for (int rep = 0; rep < 4; ++rep)
                a4[rep] = *(const float4*)(aGf + k0n + (size_t)(rep * 8) * K);
            gl_lds16(bG + k0n, &Bsl[nxt][(w * 32) * 32]);
            gl_lds16(bG + k0n + rstep16, &Bsl[nxt][(w * 32 + 16) * 32]);
        }
        short8 af[4], bfr[4];
#pragma unroll
        for (int m = 0; m < 4; ++m) af[m]  = *(const short8*)&Asl[cur][aRoff + m * 16 * 32];
#pragma unroll
        for (int n = 0; n < 4; ++n) bfr[n] = *(const short8*)&Bsl[cur][bRoff + n * 16 * 32];
#pragma unroll
        for (int m = 0; m < 4; ++m)
#pragma unroll
            for (int n = 0; n < 4; ++n)
                acc[m][n] = __builtin_amdgcn_mfma_f32_16x16x32_bf16(
                    af[m], bfr[n], acc[m][n], 0, 0, 0);
        if (has_next) {
#pragma unroll
            for (int rep = 0; rep < 4; ++rep) {
                ushort4 v{f2bf(a4[rep].x), f2bf(a4[rep].y), f2bf(a4[rep].z), f2bf(a4[rep].w)};
                *(ushort4*)&Asl[nxt][(w * 32 + rep * 8 + ar) * 32 + ac] = v;
            }
        }
        drain_barrier();
    }

#pragma unroll
    for (int n = 0; n < 4; ++n) {
        const int gc = n0 + wc + n * 16 + (lane & 15);
        if (gc >= Nreal) continue;
        const float bv = bias[gc];
        const int gr0 = m0 + wr + (lane >> 4) * 4;
#pragma unroll
        for (int m = 0; m < 4; ++m)
#pragma unroll
            for (int r = 0; r < 4; ++r)
                C[(size_t)(gr0 + m * 16 + r) * ldc + gc] = acc[m][n][r] + bv;
    }
}

// ---------------------------------------------------------------------------
// Weight prep: B^T bf16, pre-swizzled. storage[n][kd] = W[(kd^swz)][n],
// swz = (n&7)<<3 for Wv/Wo (BK=64 slices), (n&3)<<3 for W1/W2 (BK=32 slices).
// Woa: linear [128][256] (old-format for gemm_oaw) + padded bias.
// ---------------------------------------------------------------------------
__global__ __launch_bounds__(256) void prep_all(
    const float* __restrict__ Wv, const float* __restrict__ Wo,
    const float* __restrict__ W1, const float* __restrict__ W2,
    const float* __restrict__ Woff, const float* __restrict__ Waw,
    const float* __restrict__ boff, const float* __restrict__ baw,
    u16* __restrict__ Wvs, u16* __restrict__ Wos,
    u16* __restrict__ W1s, u16* __restrict__ W2s,
    u16* __restrict__ Woa, float* __restrict__ boa)
{
    const int idx = blockIdx.x * 256 + threadIdx.x;
    if (idx < 65536) {
        const int n = idx >> 8, kd = idx & 255;
        Wvs[idx] = f2bf(Wv[(size_t)(kd ^ ((n & 7) << 3)) * 256 + n]);
    } else if (idx < 131072) {
        const int i = idx - 65536, n = i >> 8, kd = i & 255;
        Wos[i] = f2bf(Wo[(size_t)(kd ^ ((n & 7) << 3)) * 256 + n]);
    } else if (idx < 393216) {
        const int i = idx - 131072, n = i >> 8, kd = i & 255;   // n: 0..1023
        W1s[i] = f2bf(W1[(size_t)(kd ^ ((n & 3) << 3)) * 1024 + n]);
    } else if (idx < 655360) {
        const int i = idx - 393216, n = i >> 10, kd = i & 1023;
        W2s[i] = f2bf(W2[(size_t)(kd ^ ((n & 3) << 3)) * 256 + n]);
    } else if (idx < 688128) {
        const int i = idx - 655360, n = i >> 8, k = i & 255;
        float v = 0.f;
        if (n < 64)      v = Woff[(size_t)k * 64 + n];
        else if (n < 96) v = Waw[(size_t)k * 32 + (n - 64)];
        Woa[i] = f2bf(v);
    } else if (idx < 688256) {
        const int i = idx - 688128;
        boa[i] = (i < 64) ? boff[i] : (i < 96 ? baw[i - 64] : 0.f);
    }
}

// ---------------------------------------------------------------------------
// Bilinear sampling + attention-weight combine (R3/R4 layout).
// ---------------------------------------------------------------------------
__global__ __launch_bounds__(256) void sample_attn(
    const u16* __restrict__ val, const float* __restrict__ oaw,
    const float* __restrict__ refp, u16* __restrict__ attn)
{
    const int t   = threadIdx.x;
    const int gid = blockIdx.x * 64 + (t >> 2);
    const int c0  = (t & 3) << 3;
    const int h   = gid & (NH_ - 1);
    const int bq  = gid >> 3;

    const float* row = oaw + (size_t)bq * 96;
    const float rx = refp[(size_t)bq * 2 + 0] * (float)WIMG;
    const float ry = refp[(size_t)bq * 2 + 1] * (float)HIMG;

    const float4 aw4 = *(const float4*)(row + 64 + h * 4);
    const float mx = fmaxf(fmaxf(aw4.x, aw4.y), fmaxf(aw4.z, aw4.w));
    const float e0 = __expf(aw4.x - mx), e1 = __expf(aw4.y - mx);
    const float e2 = __expf(aw4.z - mx), e3 = __expf(aw4.w - mx);
    const float inv = 1.f / (e0 + e1 + e2 + e3);
    const float w4[4] = {e0 * inv, e1 * inv, e2 * inv, e3 * inv};

    const int b = bq / Lq_;
    const u16* vb = val + (size_t)b * LIN * C_ + h * 32 + c0;

    float acc[8] = {};
#pragma unroll
    for (int p = 0; p < NP_; ++p) {
        const float2 off = *(const float2*)(row + (h * 4 + p) * 2);
        const float x = rx + off.x - 0.5f;
        const float y = ry + off.y - 0.5f;
        const float xf = floorf(x), yf = floorf(y);
        const float lx = x - xf, ly = y - yf;
        const int x0 = (int)xf, y0 = (int)yf;
        const float wp = w4[p];
        const float w00 = wp * (1.f - lx) * (1.f - ly);
        const float w10 = wp * lx * (1.f - ly);
        const float w01 = wp * (1.f - lx) * ly;
        const float w11 = wp * lx * ly;

#pragma unroll
        for (int c = 0; c < 4; ++c) {
            const int xi = x0 + (c & 1);
            const int yi = y0 + (c >> 1);
            const float wc = (c == 0) ? w00 : (c == 1) ? w10 : (c == 2) ? w01 : w11;
            const bool v = ((unsigned)xi < (unsigned)WIMG) & ((unsigned)yi < (unsigned)HIMG);
            const int idx = v ? (yi * WIMG + xi) : 0;
            const float w = v ? wc : 0.f;
            const short8 d = *(const short8*)(vb + (size_t)idx * C_);
#pragma unroll
            for (int j = 0; j < 8; ++j)
                acc[j] = fmaf(w, bf2f(((const u16*)&d)[j]), acc[j]);
        }
    }

    union { short8 s; u16 u[8]; } o;
#pragma unroll
    for (int j = 0; j < 8; ++j) o.u[j] = f2bf(acc[j]);
    *(short8*)(attn + (size_t)bq * C_ + h * 32 + c0) = o.s;
}

// ---------------------------------------------------------------------------
extern "C" void kernel_launch(void* const* d_in, const int* in_sizes, int n_in,
                              void* d_out, int out_size, void* d_ws, size_t ws_size,
                              hipStream_t stream)
{
    const float* query = (const float*)d_in[0];
    const float* src   = (const float*)d_in[1];
    const float* refp  = (const float*)d_in[2];
    const float* W_off = (const float*)d_in[5];
    const float* b_off = (const float*)d_in[6];
    const float* W_aw  = (const float*)d_in[7];
    const float* b_aw  = (const float*)d_in[8];
    const float* W_val = (const float*)d_in[9];
    const float* b_val = (const float*)d_in[10];
    const float* W_out = (const float*)d_in[11];
    const float* b_out = (const float*)d_in[12];
    const float* g1    = (const float*)d_in[13];
    const float* be1   = (const float*)d_in[14];
    const float* W1    = (const float*)d_in[15];
    const float* b1    = (const float*)d_in[16];
    const float* W2    = (const float*)d_in[17];
    const float* b2    = (const float*)d_in[18];
    const float* g2    = (const float*)d_in[19];
    const float* be2   = (const float*)d_in[20];
    float* out = (float*)d_out;

    char* ws = (char*)d_ws;
    const int R = B_ * Lq_;  // 80000

    // Workspace (~155 MB of ~327 MB):
    u16*  val  = (u16*)(ws + 0);           // 40.96 MB
    float* oaw = (float*)(ws + 40960000);  // 30.72 MB
    u16*  attn = (u16*)(ws + 71680000);    // 40.96 MB
    u16*  q1b  = (u16*)(ws + 112640000);   // 40.96 MB (swizzled layout)
    u16*  Wvs  = (u16*)(ws + 153600000);
    u16*  Wos  = (u16*)(ws + 153600000 + 131072);
    u16*  W1s  = (u16*)(ws + 153600000 + 262144);
    u16*  W2s  = (u16*)(ws + 153600000 + 786432);
    u16*  Woa  = (u16*)(ws + 153600000 + 1310720);
    float* boa = (float*)(ws + 153600000 + 1376256);

    prep_all<<<2689, 256, 0, stream>>>(W_val, W_out, W1, W2, W_off, W_aw,
                                       b_off, b_aw, Wvs, Wos, W1s, W2s,
                                       Woa, boa);

    // value = src @ W_val + b_val  (f32 A converted in-kernel) -> bf16 linear
    gemm256<true, false><<<625, 512, 0, stream>>>(
        src, Wvs, b_val, nullptr, nullptr, nullptr, val, 256);

    // oaw = query @ [W_off|W_aw] + bias  (N padded 96->128)
    gemm_oaw<<<dim3(1, 625), 256, 0, stream>>>(
        query, Woa, boa, oaw, R, 256, 96, 96);

    // bilinear sampling + softmax combine -> attn bf16 linear
    sample_attn<<<10000, 256, 0, stream>>>(val, oaw, refp, attn);

    // q1 = LN(query + attn @ W_out + b_out) -> q1b bf16 (swizzled layout)
    gemm256<false, true><<<625, 512, 0, stream>>>(
        attn, Wos, b_out, query, g1, be1, q1b, 256);

    // out = LN(q1 + FFN(q1)) -> f32, h stays in LDS (counted-vmcnt schedule)
    ffn_fused<<<625, 512, 0, stream>>>(q1b, W1s, W2s, b1, b2, g2, be2, out);
}

// Round 7
// 310.816 us; speedup vs baseline: 7.3927x; 1.0003x over previous
//
#include <hip/hip_runtime.h>
#include <hip/hip_bf16.h>

typedef __hip_bfloat16 bf16;
typedef unsigned short u16;
typedef short short8 __attribute__((ext_vector_type(8)));
typedef float f32x4 __attribute__((ext_vector_type(4)));

static constexpr int B_   = 8;
static constexpr int Lq_  = 10000;
static constexpr int C_   = 256;
static constexpr int NH_  = 8;
static constexpr int NP_  = 4;
static constexpr int HIMG = 100;
static constexpr int WIMG = 100;
static constexpr int LIN  = 10000;   // H*W

__device__ __forceinline__ u16 f2bf(float x) {
    union { bf16 b; u16 u; } cv; cv.b = __float2bfloat16(x); return cv.u;
}
__device__ __forceinline__ float bf2f(u16 u) {
    return __uint_as_float((unsigned)u << 16);
}

// Async global -> LDS, 16 B per lane. LDS dest wave-uniform; HW writes
// base + lane*16 (guide §5 m104).
__device__ __forceinline__ void gl_lds16(const void* g, void* l) {
    __builtin_amdgcn_global_load_lds(
        (const __attribute__((address_space(1))) void*)g,
        (__attribute__((address_space(3))) void*)l, 16, 0, 0);
}
__device__ __forceinline__ void drain_barrier() {
    asm volatile("s_waitcnt vmcnt(0) lgkmcnt(0)" ::: "memory");
    __builtin_amdgcn_s_barrier();
}
#define VMW(N) asm volatile("s_waitcnt vmcnt(" #N ")" ::: "memory")
#define LKW0() asm volatile("s_waitcnt lgkmcnt(0)" ::: "memory")
#define BAR()  __builtin_amdgcn_s_barrier()

// Swizzle convention (rule #21, both-sides-or-neither):
//   storage[row][e] = logical[row][e ^ ((row&S)<<3)]   (granule = 8 elem = 16B)
//   S=7 for >=128B rows, S=3 for 64B rows. Stagers copy storage linearly;
//   readers XOR the same pattern.

// ---------------------------------------------------------------------------
// gemm256: C[M][256] = A[M][K] @ B + bias, tile 128x256, 8 waves (2m x 4n),
// BK=64, 2-phase dbuf staging. B pre-swizzled [256][K] (S=7 per 64-elem slice).
// AF32: A is f32, reg-staged+converted; else bf16, gl_lds w/ source swizzle.
// LN: epilogue += resid (f32), row-LayerNorm(g,be), write u16 SWIZZLED (S=7).
// else: plain bias epilogue, write u16 linear.
// ---------------------------------------------------------------------------
template <bool AF32, bool LN>
__global__ __launch_bounds__(512, 2) void gemm256(
    const void* __restrict__ Av, const u16* __restrict__ Bg,
    const float* __restrict__ bias, const float* __restrict__ resid,
    const float* __restrict__ gw, const float* __restrict__ bw,
    u16* __restrict__ Co, int K)
{
    __shared__ __align__(16) u16 At[2][128 * 64];
    __shared__ __align__(16) u16 Bt[2][256 * 64];
    __shared__ float red[2][128][4];

    const int tid  = threadIdx.x;
    const int lane = tid & 63;
    const int w    = tid >> 6;
    const int wm   = w >> 2, wn = w & 3;
    const int m0   = blockIdx.x * 128;

    f32x4 acc[4][4];
#pragma unroll
    for (int i = 0; i < 4; ++i)
#pragma unroll
        for (int j = 0; j < 4; ++j) acc[i][j] = f32x4{0.f, 0.f, 0.f, 0.f};

    auto stageA = [&](int t) {
        const int kt = t << 6;
        if constexpr (AF32) {
            const int row = tid >> 2;
            const int k0  = (tid & 3) << 4;
            const float* s = (const float*)Av + (size_t)(m0 + row) * K + kt + k0;
            float4 v0 = *(const float4*)(s + 0);
            float4 v1 = *(const float4*)(s + 4);
            float4 v2 = *(const float4*)(s + 8);
            float4 v3 = *(const float4*)(s + 12);
            union { short8 s8; u16 u[8]; } ga, gb;
            ga.u[0]=f2bf(v0.x); ga.u[1]=f2bf(v0.y); ga.u[2]=f2bf(v0.z); ga.u[3]=f2bf(v0.w);
            ga.u[4]=f2bf(v1.x); ga.u[5]=f2bf(v1.y); ga.u[6]=f2bf(v1.z); ga.u[7]=f2bf(v1.w);
            gb.u[0]=f2bf(v2.x); gb.u[1]=f2bf(v2.y); gb.u[2]=f2bf(v2.z); gb.u[3]=f2bf(v2.w);
            gb.u[4]=f2bf(v3.x); gb.u[5]=f2bf(v3.y); gb.u[6]=f2bf(v3.z); gb.u[7]=f2bf(v3.w);
            u16* d = &At[t & 1][row * 64];
            *(short8*)&d[(k0)     ^ ((row & 7) << 3)] = ga.s8;
            *(short8*)&d[(k0 + 8) ^ ((row & 7) << 3)] = gb.s8;
        } else {
#pragma unroll
            for (int i = 0; i < 2; ++i) {
                const int rb  = w * 16 + i * 8;
                const int row = rb + (lane >> 3);
                const int gs  = (lane & 7) ^ (row & 7);
                gl_lds16((const u16*)Av + (size_t)(m0 + row) * K + kt + gs * 8,
                         &At[t & 1][rb * 64]);
            }
        }
    };
    auto stageB = [&](int t) {
        const int kt = t << 6;
#pragma unroll
        for (int i = 0; i < 4; ++i) {
            const int rb  = w * 32 + i * 8;
            const int row = rb + (lane >> 3);
            gl_lds16(Bg + (size_t)row * K + kt + (lane & 7) * 8,
                     &Bt[t & 1][rb * 64]);
        }
    };
    auto compute = [&](int t) {
        const u16* a = At[t & 1];
        const u16* b = Bt[t & 1];
#pragma unroll
        for (int ks = 0; ks < 2; ++ks) {
            const int ko = ks * 32 + ((lane >> 4) << 3);
            short8 bfr[4];
#pragma unroll
            for (int n = 0; n < 4; ++n) {
                const int nr = wn * 64 + n * 16 + (lane & 15);
                bfr[n] = *(const short8*)&b[nr * 64 + (ko ^ ((nr & 7) << 3))];
            }
#pragma unroll
            for (int m = 0; m < 4; ++m) {
                const int ar = wm * 64 + m * 16 + (lane & 15);
                const short8 af = *(const short8*)&a[ar * 64 + (ko ^ ((ar & 7) << 3))];
#pragma unroll
                for (int n = 0; n < 4; ++n)
                    acc[m][n] = __builtin_amdgcn_mfma_f32_16x16x32_bf16(
                        af, bfr[n], acc[m][n], 0, 0, 0);
            }
        }
    };

    stageA(0); stageB(0);
    drain_barrier();
    const int nt = K >> 6;
    for (int t = 0; t < nt; ++t) {
        if (t + 1 < nt) { stageA(t + 1); stageB(t + 1); }
        compute(t);
        drain_barrier();
    }

    // epilogue. C/D frag: col = lane&15 (+n*16+wn*64), row = (lane>>4)*4+r (+m*16+wm*64)
    float bcol[4], gcol[4], becol[4];
#pragma unroll
    for (int n = 0; n < 4; ++n) {
        const int col = wn * 64 + n * 16 + (lane & 15);
        bcol[n] = bias[col];
        if (LN) { gcol[n] = gw[col]; becol[n] = bw[col]; }
    }

    if constexpr (!LN) {
#pragma unroll
        for (int m = 0; m < 4; ++m)
#pragma unroll
            for (int r = 0; r < 4; ++r) {
                const int lr = wm * 64 + m * 16 + (lane >> 4) * 4 + r;
#pragma unroll
                for (int n = 0; n < 4; ++n) {
                    const int col = wn * 64 + n * 16 + (lane & 15);
                    Co[(size_t)(m0 + lr) * 256 + col] = f2bf(acc[m][n][r] + bcol[n]);
                }
            }
    } else {
        float s[4][4], s2[4][4];
#pragma unroll
        for (int m = 0; m < 4; ++m)
#pragma unroll
            for (int r = 0; r < 4; ++r) {
                const int lr = wm * 64 + m * 16 + (lane >> 4) * 4 + r;
                float ps = 0.f, ps2 = 0.f;
#pragma unroll
                for (int n = 0; n < 4; ++n) {
                    const int col = wn * 64 + n * 16 + (lane & 15);
                    float v = acc[m][n][r] + bcol[n]
                            + resid[(size_t)(m0 + lr) * 256 + col];
                    acc[m][n][r] = v;
                    ps += v; ps2 += v * v;
                }
#pragma unroll
                for (int o = 1; o < 16; o <<= 1) {
                    ps  += __shfl_xor(ps,  o);
                    ps2 += __shfl_xor(ps2, o);
                }
                s[m][r] = ps; s2[m][r] = ps2;
            }
        if ((lane & 15) == 0) {
#pragma unroll
            for (int m = 0; m < 4; ++m)
#pragma unroll
                for (int r = 0; r < 4; ++r) {
                    const int lr = wm * 64 + m * 16 + (lane >> 4) * 4 + r;
                    red[0][lr][wn] = s[m][r];
                    red[1][lr][wn] = s2[m][r];
                }
        }
        __syncthreads();
        if (tid < 128) {
            const float ss  = red[0][tid][0] + red[0][tid][1] + red[0][tid][2] + red[0][tid][3];
            const float ss2 = red[1][tid][0] + red[1][tid][1] + red[1][tid][2] + red[1][tid][3];
            const float mean = ss * (1.f / 256.f);
            const float var  = fmaxf(ss2 * (1.f / 256.f) - mean * mean, 0.f);
            red[0][tid][0] = mean;
            red[1][tid][0] = rsqrtf(var + 1e-5f);
        }
        __syncthreads();
#pragma unroll
        for (int m = 0; m < 4; ++m)
#pragma unroll
            for (int r = 0; r < 4; ++r) {
                const int lr = wm * 64 + m * 16 + (lane >> 4) * 4 + r;
                const float mean = red[0][lr][0];
                const float rstd = red[1][lr][0];
#pragma unroll
                for (int n = 0; n < 4; ++n) {
                    const int col = wn * 64 + n * 16 + (lane & 15);
                    const float o = (acc[m][n][r] - mean) * rstd * gcol[n] + becol[n];
                    Co[(size_t)(m0 + lr) * 256 + (col ^ ((lr & 7) << 3))] = f2bf(o);
                }
            }
    }
}

// ---------------------------------------------------------------------------
// ffn_fused v2 — counted-vmcnt schedule (T4), no drains in main loop.
// Per 128-row block: As resident (swizzled q1b). 8 chunks of DFF=128:
//   GEMM1 (8 steps, BK=32): B1 ring-3, issue 2 ahead, vmcnt(1)/step.
//   Hs (padded ld=136) <- relu(acc1+b1).
//   GEMM2 (4 steps, BK=32): B2 ring-2; B2_0/1 prefetched during G1 t6/t7;
//   next-chunk B1_0..2 prefetched during G2 u0..u2.
// One s_barrier per step; waits are counted so loads span barriers.
// ---------------------------------------------------------------------------
__global__ __launch_bounds__(512) void ffn_fused(
    const u16* __restrict__ q1b, const u16* __restrict__ W1s,
    const u16* __restrict__ W2s, const float* __restrict__ b1,
    const float* __restrict__ b2, const float* __restrict__ g2,
    const float* __restrict__ be2, float* __restrict__ out)
{
    __shared__ __align__(16) u16 As[128 * 256];      // 64 KB, resident
    __shared__ __align__(16) u16 Hs[128 * 136];      // 34 KB, padded (no swz)
    __shared__ __align__(16) u16 B1t[3][128 * 32];   // 24 KB ring
    __shared__ __align__(16) u16 B2t[2][256 * 32];   // 32 KB ring
    // red aliases Hs (only used in epilogue, after last Hs read)
    float (*red)[128][4] = (float (*)[128][4])Hs;

    const int tid  = threadIdx.x;
    const int lane = tid & 63;
    const int w    = tid >> 6;
    const int wm   = w >> 2, wn = w & 3;
    const int m0   = blockIdx.x * 128;

    f32x4 acc2[4][4];
#pragma unroll
    for (int i = 0; i < 4; ++i)
#pragma unroll
        for (int j = 0; j < 4; ++j) acc2[i][j] = f32x4{0.f, 0.f, 0.f, 0.f};

    // per wave: 1 load
    auto issueB1 = [&](int c, int t, int buf) {
        const int rb  = w * 16;
        const int row = rb + (lane >> 2);
        gl_lds16(W1s + (size_t)(c * 128 + row) * 256 + t * 32 + (lane & 3) * 8,
                 &B1t[buf][rb * 32]);
    };
    // per wave: 2 loads
    auto issueB2 = [&](int c, int u, int buf) {
#pragma unroll
        for (int i = 0; i < 2; ++i) {
            const int rb  = i * 128 + w * 16;
            const int row = rb + (lane >> 2);
            gl_lds16(W2s + (size_t)row * 1024 + c * 128 + u * 32 + (lane & 3) * 8,
                     &B2t[buf][rb * 32]);
        }
    };

    // ---- prologue: As (8 loads/wave) + B1 bufs 0..2 for chunk 0
#pragma unroll
    for (int i = 0; i < 8; ++i) {
        const int rb = w * 16 + i * 2;
        gl_lds16(q1b + (size_t)(m0 + rb + (lane >> 5)) * 256 + (lane & 31) * 8,
                 &As[rb * 256]);
    }
    issueB1(0, 0, 0); issueB1(0, 1, 1); issueB1(0, 2, 2);
    VMW(2); BAR();   // B1_0 + As done (B1_1, B1_2 may be in flight)

    for (int c = 0; c < 8; ++c) {
        f32x4 acc1[4][2];
#pragma unroll
        for (int i = 0; i < 4; ++i)
#pragma unroll
            for (int j = 0; j < 2; ++j) acc1[i][j] = f32x4{0.f, 0.f, 0.f, 0.f};

        auto g1 = [&](int t, int buf) {
            const u16* bb = B1t[buf];
            const int ko = (lane >> 4) << 3;
            short8 bfr[2];
#pragma unroll
            for (int n = 0; n < 2; ++n) {
                const int nr = wn * 32 + n * 16 + (lane & 15);
                bfr[n] = *(const short8*)&bb[nr * 32 + (ko ^ ((nr & 3) << 3))];
            }
#pragma unroll
            for (int m = 0; m < 4; ++m) {
                const int ar = wm * 64 + m * 16 + (lane & 15);
                const short8 af = *(const short8*)
                    &As[ar * 256 + ((t * 32 + ko) ^ ((ar & 7) << 3))];
#pragma unroll
                for (int n = 0; n < 2; ++n)
                    acc1[m][n] = __builtin_amdgcn_mfma_f32_16x16x32_bf16(
                        af, bfr[n], acc1[m][n], 0, 0, 0);
            }
        };
        auto g2s = [&](int u, int buf) {
            const u16* bb = B2t[buf];
            const int ko = (lane >> 4) << 3;
            short8 bfr[4];
#pragma unroll
            for (int n = 0; n < 4; ++n) {
                const int nr = wn * 64 + n * 16 + (lane & 15);
                bfr[n] = *(const short8*)&bb[nr * 32 + (ko ^ ((nr & 3) << 3))];
            }
#pragma unroll
            for (int m = 0; m < 4; ++m) {
                const int hr = wm * 64 + m * 16 + (lane & 15);
                const short8 af = *(const short8*)&Hs[hr * 136 + u * 32 + ko];
#pragma unroll
                for (int n = 0; n < 4; ++n)
                    acc2[m][n] = __builtin_amdgcn_mfma_f32_16x16x32_bf16(
                        af, bfr[n], acc2[m][n], 0, 0, 0);
            }
        };

        // ---- GEMM1, 8 steps, one barrier each, counted waits
        g1(0, 0);
        if (c == 0) { VMW(1); } else { VMW(3); }   // B1_1 ready
        BAR();
        issueB1(c, 3, 0); g1(1, 1); VMW(1); BAR();  // B1_2 ready
        issueB1(c, 4, 1); g1(2, 2); VMW(1); BAR();
        issueB1(c, 5, 2); g1(3, 0); VMW(1); BAR();
        issueB1(c, 6, 0); g1(4, 1); VMW(1); BAR();
        issueB1(c, 7, 1); g1(5, 2); VMW(1); BAR();
        issueB2(c, 0, 0); g1(6, 0); VMW(2); BAR();  // B1_7 ready
        issueB2(c, 1, 1); g1(7, 1); VMW(2); BAR();  // B2_0 ready

        // ---- h -> Hs (bias+relu), padded rows (bank-rotating, no swizzle)
#pragma unroll
        for (int n = 0; n < 2; ++n) {
            const int col = wn * 32 + n * 16 + (lane & 15);
            const float bb = b1[c * 128 + col];
#pragma unroll
            for (int m = 0; m < 4; ++m)
#pragma unroll
                for (int r = 0; r < 4; ++r) {
                    const int row = wm * 64 + m * 16 + (lane >> 4) * 4 + r;
                    Hs[row * 136 + col] = f2bf(fmaxf(acc1[m][n][r] + bb, 0.f));
                }
        }
        LKW0(); BAR();

        // ---- GEMM2, 4 steps; prefetch next-chunk B1 (c=7 reads into W2s
        // region -> valid memory, data unused)
        issueB1(c + 1, 0, 0);                    g2s(0, 0); VMW(1); BAR(); // B2_1 ready
        issueB2(c, 2, 0); issueB1(c + 1, 1, 1);  g2s(1, 1); VMW(1); BAR(); // B2_2 ready
        issueB2(c, 3, 1); issueB1(c + 1, 2, 2);  g2s(2, 0); VMW(1); BAR(); // B2_3 ready
        g2s(3, 1); VMW(6); BAR();                // next-chunk B1_0 ready
    }
    asm volatile("s_waitcnt vmcnt(0)" ::: "memory");
    BAR();

    // ---- epilogue: LN2(q1 (from As) + acc2 + b2) -> out f32
    float bcol[4], gcol[4], becol[4];
#pragma unroll
    for (int n = 0; n < 4; ++n) {
        const int col = wn * 64 + n * 16 + (lane & 15);
        bcol[n] = b2[col]; gcol[n] = g2[col]; becol[n] = be2[col];
    }
    float s[4][4], s2[4][4];
#pragma unroll
    for (int m = 0; m < 4; ++m)
#pragma unroll
        for (int r = 0; r < 4; ++r) {
            const int lr = wm * 64 + m * 16 + (lane >> 4) * 4 + r;
            float ps = 0.f, ps2 = 0.f;
#pragma unroll
            for (int n = 0; n < 4; ++n) {
                const int col = wn * 64 + n * 16 + (lane & 15);
                const float q = bf2f(As[lr * 256 + (col ^ ((lr & 7) << 3))]);
                const float v = acc2[m][n][r] + bcol[n] + q;
                acc2[m][n][r] = v;
                ps += v; ps2 += v * v;
            }
#pragma unroll
            for (int o = 1; o < 16; o <<= 1) {
                ps  += __shfl_xor(ps,  o);
                ps2 += __shfl_xor(ps2, o);
            }
            s[m][r] = ps; s2[m][r] = ps2;
        }
    if ((lane & 15) == 0) {
#pragma unroll
        for (int m = 0; m < 4; ++m)
#pragma unroll
            for (int r = 0; r < 4; ++r) {
                const int lr = wm * 64 + m * 16 + (lane >> 4) * 4 + r;
                red[0][lr][wn] = s[m][r];
                red[1][lr][wn] = s2[m][r];
            }
    }
    __syncthreads();
    if (tid < 128) {
        const float ss  = red[0][tid][0] + red[0][tid][1] + red[0][tid][2] + red[0][tid][3];
        const float ss2 = red[1][tid][0] + red[1][tid][1] + red[1][tid][2] + red[1][tid][3];
        const float mean = ss * (1.f / 256.f);
        const float var  = fmaxf(ss2 * (1.f / 256.f) - mean * mean, 0.f);
        red[0][tid][0] = mean;
        red[1][tid][0] = rsqrtf(var + 1e-5f);
    }
    __syncthreads();
#pragma unroll
    for (int m = 0; m < 4; ++m)
#pragma unroll
        for (int r = 0; r < 4; ++r) {
            const int lr = wm * 64 + m * 16 + (lane >> 4) * 4 + r;
            const float mean = red[0][lr][0];
            const float rstd = red[1][lr][0];
#pragma unroll
            for (int n = 0; n < 4; ++n) {
                const int col = wn * 64 + n * 16 + (lane & 15);
                out[(size_t)(m0 + lr) * 256 + col] =
                    (acc2[m][n][r] - mean) * rstd * gcol[n] + becol[n];
            }
        }
}

// ---------------------------------------------------------------------------
// 4-wave 128x128 MFMA GEMM (R4 structure) — used only for the oaw projection.
// ---------------------------------------------------------------------------
__global__ __launch_bounds__(256) void gemm_oaw(
    const float* __restrict__ Av, const u16* __restrict__ Bt,
    const float* __restrict__ bias, float* __restrict__ C,
    int M, int K, int Nreal, int ldc)
{
    __shared__ __align__(16) u16 Asl[2][128 * 32];
    __shared__ __align__(16) u16 Bsl[2][128 * 32];

    const int tid  = threadIdx.x;
    const int lane = tid & 63;
    const int w    = tid >> 6;
    const int wr   = (w >> 1) * 64;
    const int wc   = (w & 1) * 64;
    const int m0   = blockIdx.y * 128;
    const int n0   = blockIdx.x * 128;

    const int srow = lane >> 2;
    const int scol = (lane & 3) << 3;
    const u16* bG = Bt + (size_t)(n0 + w * 32 + srow) * K + scol;
    const size_t rstep16 = (size_t)16 * K;

    const int ar  = lane >> 3;
    const int ac  = (lane & 7) << 2;
    const float* aGf = Av + (size_t)(m0 + w * 32 + ar) * K + ac;

    const int aRoff = (wr + (lane & 15)) * 32 + (lane >> 4) * 8;
    const int bRoff = (wc + (lane & 15)) * 32 + (lane >> 4) * 8;

    f32x4 acc[4][4];
#pragma unroll
    for (int i = 0; i < 4; ++i)
#pragma unroll
        for (int j = 0; j < 4; ++j) acc[i][j] = f32x4{0.f, 0.f, 0.f, 0.f};

    float4 a4[4];
    const int nt = K >> 5;

#pragma unroll
    for (int rep = 0; rep < 4; ++rep)
        a4[rep] = *(const float4*)(aGf + (size_t)(rep * 8) * K);
#pragma unroll
    for (int rep = 0; rep < 4; ++rep) {
        ushort4 v{f2bf(a4[rep].x), f2bf(a4[rep].y), f2bf(a4[rep].z), f2bf(a4[rep].w)};
        *(ushort4*)&Asl[0][(w * 32 + rep * 8 + ar) * 32 + ac] = v;
    }
    gl_lds16(bG, &Bsl[0][(w * 32) * 32]);
    gl_lds16(bG + rstep16, &Bsl[0][(w * 32 + 16) * 32]);
    drain_barrier();

    for (int t = 0; t < nt; ++t) {
        const int cur = t & 1, nxt = cur ^ 1;
        const int k0n = (t + 1) << 5;
        const bool has_next = (t + 1 < nt);
        if (has_next) {
#pragma unroll
            for (int rep = 0; rep < 4; ++rep)
                a4[rep] = *(const float4*)(aGf + k0n + (size_t)(rep * 8) * K);
            gl_lds16(bG + k0n, &Bsl[nxt][(w * 32) * 32]);
            gl_lds16(bG + k0n + rstep16, &Bsl[nxt][(w * 32 + 16) * 32]);
        }
        short8 af[4], bfr[4];
#pragma unroll
        for (int m = 0; m < 4; ++m) af[m]  = *(const short8*)&Asl[cur][aRoff + m * 16 * 32];
#pragma unroll
        for (int n = 0; n < 4; ++n) bfr[n] = *(const short8*)&Bsl[cur][bRoff + n * 16 * 32];
#pragma unroll
        for (int m = 0; m < 4; ++m)
#pragma unroll
            for (int n = 0; n < 4; ++n)
                acc[m][n] = __builtin_amdgcn_mfma_f32_16x16x32_bf16(
                    af[m], bfr[n], acc[m][n], 0, 0, 0);
        if (has_next) {
#pragma unroll
            for (int rep = 0; rep < 4; ++rep) {
                ushort4 v{f2bf(a4[rep].x), f2bf(a4[rep].y), f2bf(a4[rep].z), f2bf(a4[rep].w)};
                *(ushort4*)&Asl[nxt][(w * 32 + rep * 8 + ar) * 32 + ac] = v;
            }
        }
        drain_barrier();
    }

#pragma unroll
    for (int n = 0; n < 4; ++n) {
        const int gc = n0 + wc + n * 16 + (lane & 15);
        if (gc >= Nreal) continue;
        const float bv = bias[gc];
        const int gr0 = m0 + wr + (lane >> 4) * 4;
#pragma unroll
        for (int m = 0; m < 4; ++m)
#pragma unroll
            for (int r = 0; r < 4; ++r)
                C[(size_t)(gr0 + m * 16 + r) * ldc + gc] = acc[m][n][r] + bv;
    }
}

// ---------------------------------------------------------------------------
// Weight prep: B^T bf16, pre-swizzled. storage[n][kd] = W[(kd^swz)][n],
// swz = (n&7)<<3 for Wv/Wo (BK=64 slices), (n&3)<<3 for W1/W2 (BK=32 slices).
// Woa: linear [128][256] (old-format for gemm_oaw) + padded bias.
// ---------------------------------------------------------------------------
__global__ __launch_bounds__(256) void prep_all(
    const float* __restrict__ Wv, const float* __restrict__ Wo,
    const float* __restrict__ W1, const float* __restrict__ W2,
    const float* __restrict__ Woff, const float* __restrict__ Waw,
    const float* __restrict__ boff, const float* __restrict__ baw,
    u16* __restrict__ Wvs, u16* __restrict__ Wos,
    u16* __restrict__ W1s, u16* __restrict__ W2s,
    u16* __restrict__ Woa, float* __restrict__ boa)
{
    const int idx = blockIdx.x * 256 + threadIdx.x;
    if (idx < 65536) {
        const int n = idx >> 8, kd = idx & 255;
        Wvs[idx] = f2bf(Wv[(size_t)(kd ^ ((n & 7) << 3)) * 256 + n]);
    } else if (idx < 131072) {
        const int i = idx - 65536, n = i >> 8, kd = i & 255;
        Wos[i] = f2bf(Wo[(size_t)(kd ^ ((n & 7) << 3)) * 256 + n]);
    } else if (idx < 393216) {
        const int i = idx - 131072, n = i >> 8, kd = i & 255;   // n: 0..1023
        W1s[i] = f2bf(W1[(size_t)(kd ^ ((n & 3) << 3)) * 1024 + n]);
    } else if (idx < 655360) {
        const int i = idx - 393216, n = i >> 10, kd = i & 1023;
        W2s[i] = f2bf(W2[(size_t)(kd ^ ((n & 3) << 3)) * 256 + n]);
    } else if (idx < 688128) {
        const int i = idx - 655360, n = i >> 8, k = i & 255;
        float v = 0.f;
        if (n < 64)      v = Woff[(size_t)k * 64 + n];
        else if (n < 96) v = Waw[(size_t)k * 32 + (n - 64)];
        Woa[i] = f2bf(v);
    } else if (idx < 688256) {
        const int i = idx - 688128;
        boa[i] = (i < 64) ? boff[i] : (i < 96 ? baw[i - 64] : 0.f);
    }
}

// ---------------------------------------------------------------------------
// Bilinear sampling + attention-weight combine (R3/R4 layout).
// ---------------------------------------------------------------------------
__global__ __launch_bounds__(256) void sample_attn(
    const u16* __restrict__ val, const float* __restrict__ oaw,
    const float* __restrict__ refp, u16* __restrict__ attn)
{
    const int t   = threadIdx.x;
    const int gid = blockIdx.x * 64 + (t >> 2);
    const int c0  = (t & 3) << 3;
    const int h   = gid & (NH_ - 1);
    const int bq  = gid >> 3;

    const float* row = oaw + (size_t)bq * 96;
    const float rx = refp[(size_t)bq * 2 + 0] * (float)WIMG;
    const float ry = refp[(size_t)bq * 2 + 1] * (float)HIMG;

    const float4 aw4 = *(const float4*)(row + 64 + h * 4);
    const float mx = fmaxf(fmaxf(aw4.x, aw4.y), fmaxf(aw4.z, aw4.w));
    const float e0 = __expf(aw4.x - mx), e1 = __expf(aw4.y - mx);
    const float e2 = __expf(aw4.z - mx), e3 = __expf(aw4.w - mx);
    const float inv = 1.f / (e0 + e1 + e2 + e3);
    const float w4[4] = {e0 * inv, e1 * inv, e2 * inv, e3 * inv};

    const int b = bq / Lq_;
    const u16* vb = val + (size_t)b * LIN * C_ + h * 32 + c0;

    float acc[8] = {};
#pragma unroll
    for (int p = 0; p < NP_; ++p) {
        const float2 off = *(const float2*)(row + (h * 4 + p) * 2);
        const float x = rx + off.x - 0.5f;
        const float y = ry + off.y - 0.5f;
        const float xf = floorf(x), yf = floorf(y);
        const float lx = x - xf, ly = y - yf;
        const int x0 = (int)xf, y0 = (int)yf;
        const float wp = w4[p];
        const float w00 = wp * (1.f - lx) * (1.f - ly);
        const float w10 = wp * lx * (1.f - ly);
        const float w01 = wp * (1.f - lx) * ly;
        const float w11 = wp * lx * ly;

#pragma unroll
        for (int c = 0; c < 4; ++c) {
            const int xi = x0 + (c & 1);
            const int yi = y0 + (c >> 1);
            const float wc = (c == 0) ? w00 : (c == 1) ? w10 : (c == 2) ? w01 : w11;
            const bool v = ((unsigned)xi < (unsigned)WIMG) & ((unsigned)yi < (unsigned)HIMG);
            const int idx = v ? (yi * WIMG + xi) : 0;
            const float w = v ? wc : 0.f;
            const short8 d = *(const short8*)(vb + (size_t)idx * C_);
#pragma unroll
            for (int j = 0; j < 8; ++j)
                acc[j] = fmaf(w, bf2f(((const u16*)&d)[j]), acc[j]);
        }
    }

    union { short8 s; u16 u[8]; } o;
#pragma unroll
    for (int j = 0; j < 8; ++j) o.u[j] = f2bf(acc[j]);
    *(short8*)(attn + (size_t)bq * C_ + h * 32 + c0) = o.s;
}

// ---------------------------------------------------------------------------
extern "C" void kernel_launch(void* const* d_in, const int* in_sizes, int n_in,
                              void* d_out, int out_size, void* d_ws, size_t ws_size,
                              hipStream_t stream)
{
    const float* query = (const float*)d_in[0];
    const float* src   = (const float*)d_in[1];
    const float* refp  = (const float*)d_in[2];
    const float* W_off = (const float*)d_in[5];
    const float* b_off = (const float*)d_in[6];
    const float* W_aw  = (const float*)d_in[7];
    const float* b_aw  = (const float*)d_in[8];
    const float* W_val = (const float*)d_in[9];
    const float* b_val = (const float*)d_in[10];
    const float* W_out = (const float*)d_in[11];
    const float* b_out = (const float*)d_in[12];
    const float* g1    = (const float*)d_in[13];
    const float* be1   = (const float*)d_in[14];
    const float* W1    = (const float*)d_in[15];
    const float* b1    = (const float*)d_in[16];
    const float* W2    = (const float*)d_in[17];
    const float* b2    = (const float*)d_in[18];
    const float* g2    = (const float*)d_in[19];
    const float* be2   = (const float*)d_in[20];
    float* out = (float*)d_out;

    char* ws = (char*)d_ws;
    const int R = B_ * Lq_;  // 80000

    // Workspace (~155 MB of ~327 MB):
    u16*  val  = (u16*)(ws + 0);           // 40.96 MB
    float* oaw = (float*)(ws + 40960000);  // 30.72 MB
    u16*  attn = (u16*)(ws + 71680000);    // 40.96 MB
    u16*  q1b  = (u16*)(ws + 112640000);   // 40.96 MB (swizzled layout)
    u16*  Wvs  = (u16*)(ws + 153600000);
    u16*  Wos  = (u16*)(ws + 153600000 + 131072);
    u16*  W1s  = (u16*)(ws + 153600000 + 262144);
    u16*  W2s  = (u16*)(ws + 153600000 + 786432);
    u16*  Woa  = (u16*)(ws + 153600000 + 1310720);
    float* boa = (float*)(ws + 153600000 + 1376256);

    prep_all<<<2689, 256, 0, stream>>>(W_val, W_out, W1, W2, W_off, W_aw,
                                       b_off, b_aw, Wvs, Wos, W1s, W2s,
                                       Woa, boa);

    // value = src @ W_val + b_val  (f32 A converted in-kernel) -> bf16 linear
    gemm256<true, false><<<625, 512, 0, stream>>>(
        src, Wvs, b_val, nullptr, nullptr, nullptr, val, 256);

    // oaw = query @ [W_off|W_aw] + bias  (N padded 96->128)
    gemm_oaw<<<dim3(1, 625), 256, 0, stream>>>(
        query, Woa, boa, oaw, R, 256, 96, 96);

    // bilinear sampling + softmax combine -> attn bf16 linear
    sample_attn<<<10000, 256, 0, stream>>>(val, oaw, refp, attn);

    // q1 = LN(query + attn @ W_out + b_out) -> q1b bf16 (swizzled layout)
    gemm256<false, true><<<625, 512, 0, stream>>>(
        attn, Wos, b_out, query, g1, be1, q1b, 256);

    // out = LN(q1 + FFN(q1)) -> f32, h stays in LDS (counted-vmcnt schedule)
    ffn_fused<<<625, 512, 0, stream>>>(q1b, W1s, W2s, b1, b2, g2, be2, out);
}